// Round 5
// baseline (169.090 us; speedup 1.0000x reference)
//
#include <hip/hip_runtime.h>
#include <hip/hip_bf16.h>

#define S_LEN 2048
#define NH 16
#define DKH 64
#define DM 1024
// 1/sqrt(64) * log2(e): folded into Q at the QKV-GEMM epilogue
#define QK_SCALE_L2E 0.1803368801111244f

typedef __attribute__((ext_vector_type(8))) short bf16x8;
typedef __attribute__((ext_vector_type(4))) float f32x4;
typedef __attribute__((ext_vector_type(4))) unsigned int u32x4;

__device__ __forceinline__ unsigned short f2bf(float f) {
  unsigned int x = __builtin_bit_cast(unsigned int, f);
  x += 0x7fffu + ((x >> 16) & 1u);   // RNE
  return (unsigned short)(x >> 16);
}
__device__ __forceinline__ float bf2f(unsigned short u) {
  unsigned int x = ((unsigned int)u) << 16;
  return __builtin_bit_cast(float, x);
}
// hardware exp2 (1 TRANS op; denorm-flush fine for softmax)
__device__ __forceinline__ float exp2a(float x) {
  float r; asm("v_exp_f32 %0, %1" : "=v"(r) : "v"(x)); return r;
}
// pack 2 fp32 -> 2 bf16 in one op: D.lo = a, D.hi = b
__device__ __forceinline__ unsigned int cvtpk(float a, float b) {
  unsigned int r; asm("v_cvt_pk_bf16_f32 %0, %1, %2" : "=v"(r) : "v"(a), "v"(b)); return r;
}

__device__ __forceinline__ void gload_lds16(const void* g, void* l) {
  __builtin_amdgcn_global_load_lds(
      (const __attribute__((address_space(1))) unsigned int*)g,
      (__attribute__((address_space(3))) unsigned int*)l, 16, 0, 0);
}

// ---------------- fp32 -> bf16 conversion (memory-bound pre-pass) -----------
__global__ void cvt_f32_to_bf16(const float* __restrict__ in,
                                unsigned short* __restrict__ out, int n) {
  int i = (blockIdx.x * blockDim.x + threadIdx.x) * 8;
  if (i >= n) return;
  float4 a = *(const float4*)(in + i);
  float4 b = *(const float4*)(in + i + 4);
  union { unsigned short us[8]; u32x4 v; } r;
  r.us[0] = f2bf(a.x); r.us[1] = f2bf(a.y); r.us[2] = f2bf(a.z); r.us[3] = f2bf(a.w);
  r.us[4] = f2bf(b.x); r.us[5] = f2bf(b.y); r.us[6] = f2bf(b.z); r.us[7] = f2bf(b.w);
  *(u32x4*)(out + i) = r.v;
}

// ---------------- 256x256 bf16 GEMM, C = A * B^T, BK=32, 8 waves ------------
// T3-min 2-phase: STAGE(next) -> ds_read+MFMA(cur) -> drain+barrier per tile.
// LDS per K-tile: 256 rows x 32 bf16 (64B) packed as 128 row-pairs x 128B,
// XOR-swizzled so wave b128 reads match the contiguous-ideal bank pattern.
// MODE 0: QKV epilogue (scatter q/k scaled, v transposed); MODE 1: fp32+bias.
template<int MODE>
__global__ __launch_bounds__(512) void gemm256(
    const unsigned short* __restrict__ A,   // [M,K] bf16 row-major
    const unsigned short* __restrict__ Bt,  // [N,K] bf16 row-major
    const float* __restrict__ bias,         // [N]
    float* __restrict__ Cf,                 // MODE 1
    unsigned short* __restrict__ qo,        // MODE 0
    unsigned short* __restrict__ ko,
    unsigned short* __restrict__ vto,
    int M, int N, int K)
{
  __shared__ __align__(16) char As[2][128 * 128];   // 16KB per slot
  __shared__ __align__(16) char Bs[2][128 * 128];
  int t = threadIdx.x;
  int lane = t & 63, wid = t >> 6;
  int wr = wid >> 2, wc = wid & 3;         // 2(M) x 4(N) waves
  int m0 = blockIdx.y << 8, n0 = blockIdx.x << 8;
  int gi = lane >> 4, c0 = lane & 15;
  int rs = t >> 3, uP = t & 7;

  f32x4 acc[8][4];
#pragma unroll
  for (int m = 0; m < 8; ++m)
#pragma unroll
    for (int n = 0; n < 4; ++n) acc[m][n] = (f32x4){0.f, 0.f, 0.f, 0.f};

  // staging: thread covers LDS pairs rs and rs+64 for A and B.
  // LDS dest (linear, = wave base + lane*16): pair*128 + uP*16
  // global src (pre-swizzled): w = uP ^ (rs&7); row = 2*pair + (w>>2); chunk = w&3
  int w1 = uP ^ (rs & 7);
  int r1 = 2 * rs + (w1 >> 2);
  int c1 = (w1 & 3) * 8;
  const unsigned short* a1 = A  + (size_t)(m0 + r1) * K + c1;
  const unsigned short* a2 = a1 + (size_t)128 * K;
  const unsigned short* b1 = Bt + (size_t)(n0 + r1) * K + c1;
  const unsigned short* b2 = b1 + (size_t)128 * K;
  int l1 = rs * 128 + uP * 16;
  int l2 = l1 + 64 * 128;

#define STAGE256(slot)                                   \
  do {                                                   \
    gload_lds16(a1, As[slot] + l1);                      \
    gload_lds16(a2, As[slot] + l2);                      \
    gload_lds16(b1, Bs[slot] + l1);                      \
    gload_lds16(b2, Bs[slot] + l2);                      \
    a1 += 32; a2 += 32; b1 += 32; b2 += 32;              \
  } while (0)

  int NT = K >> 5;
  STAGE256(0);
  __syncthreads();   // drains vmcnt -> slot 0 resident

  for (int kt = 0; kt < NT; ++kt) {
    int cur = kt & 1;
    if (kt + 1 < NT) STAGE256(cur ^ 1);   // issue next tile early; lands under compute

    bf16x8 bfr[4];
#pragma unroll
    for (int n = 0; n < 4; ++n) {
      int rb = wc * 64 + n * 16 + c0;
      int u = (((rb & 1) << 2) + gi) ^ ((rb >> 1) & 7);
      bfr[n] = *(const bf16x8*)(Bs[cur] + (rb >> 1) * 128 + u * 16);
    }
#pragma unroll
    for (int m = 0; m < 8; ++m) {
      int ra = wr * 128 + m * 16 + c0;
      int u = (((ra & 1) << 2) + gi) ^ ((ra >> 1) & 7);
      bf16x8 af = *(const bf16x8*)(As[cur] + (ra >> 1) * 128 + u * 16);
#pragma unroll
      for (int n = 0; n < 4; ++n)
        acc[m][n] = __builtin_amdgcn_mfma_f32_16x16x32_bf16(af, bfr[n], acc[m][n], 0, 0, 0);
    }
    __syncthreads();   // drains vmcnt (next tile landed) + all reads of cur done
  }
#undef STAGE256

  float bias_v[4];
#pragma unroll
  for (int n = 0; n < 4; ++n) bias_v[n] = bias[n0 + wc * 64 + n * 16 + c0];

#pragma unroll
  for (int m = 0; m < 8; ++m) {
#pragma unroll
    for (int n = 0; n < 4; ++n) {
#pragma unroll
      for (int rI = 0; rI < 4; ++rI) {
        int mm = m0 + wr * 128 + m * 16 + gi * 4 + rI;
        int nn = n0 + wc * 64 + n * 16 + c0;
        float v = acc[m][n][rI] + bias_v[n];
        if (MODE == 1) {
          Cf[(size_t)mm * N + nn] = v;
        } else {
          int b = mm >> 11, s = mm & 2047;
          int which = nn >> 10, w2 = nn & 1023;
          int h = w2 >> 6, dk = w2 & 63;
          size_t hoff = (size_t)(b * NH + h);
          if (which == 0) {
            qo[(hoff * S_LEN + s) * DKH + dk] = f2bf(v * QK_SCALE_L2E);
          } else if (which == 1) {
            ko[(hoff * S_LEN + s) * DKH + dk] = f2bf(v);
          } else {
            vto[(hoff * DKH + dk) * S_LEN + s] = f2bf(v);  // V transposed
          }
        }
      }
    }
  }
}

// ---------------- split-KV flash attention work table (LPT order) -----------
struct WorkItem { unsigned char qt, t0, nt; };
__device__ __constant__ WorkItem g_items[48] = {
  {15,0,16},
  {16,0,16},{17,0,16},{18,0,16},{19,0,16},{20,0,16},{21,0,16},{22,0,16},{23,0,16},
  {24,0,16},{25,0,16},{26,0,16},{27,0,16},{28,0,16},{29,0,16},{30,0,16},{31,0,16},
  {31,16,16},
  {14,0,15},{30,16,15},
  {13,0,14},{29,16,14},
  {12,0,13},{28,16,13},
  {11,0,12},{27,16,12},
  {10,0,11},{26,16,11},
  { 9,0,10},{25,16,10},
  { 8,0, 9},{24,16, 9},
  { 7,0, 8},{23,16, 8},
  { 6,0, 7},{22,16, 7},
  { 5,0, 6},{21,16, 6},
  { 4,0, 5},{20,16, 5},
  { 3,0, 4},{19,16, 4},
  { 2,0, 3},{18,16, 3},
  { 1,0, 2},{17,16, 2},
  { 0,0, 1},{16,16, 1},
};

// ---------------- flash attention (partial), swapped-QK^T in-reg softmax ----
__global__ __launch_bounds__(256) void attn_part(
    const unsigned short* __restrict__ Q,   // [BH, S, 64] bf16, pre-scaled
    const unsigned short* __restrict__ Kb,  // [BH, S, 64] bf16
    const unsigned short* __restrict__ Vt,  // [BH, 64, S] bf16
    unsigned short* __restrict__ pO,        // [1536][64][64] bf16
    float* __restrict__ pm,                 // [1536][64]
    float* __restrict__ pl)                 // [1536][64]
{
  __shared__ __align__(16) char kbuf[64 * 128];
  __shared__ __align__(16) char vbuf[2][64 * 128];
  __shared__ __align__(16) unsigned short pbuf[4][16][88];  // 176B rows
  int t = threadIdx.x;
  int lane = t & 63, wid = t >> 6;
  int gi = lane >> 4, c0 = lane & 15;
  WorkItem wi = g_items[blockIdx.x];
  int bh = blockIdx.y;
  int qt = wi.qt, tile0 = wi.t0, nt = wi.nt;
  int pid = bh * 48 + (tile0 ? (32 + qt - 16) : qt);
  int q0 = qt << 6;
  const unsigned short* Qh = Q  + (size_t)bh * S_LEN * DKH;
  const unsigned short* Kh = Kb + (size_t)bh * S_LEN * DKH;
  const unsigned short* Vh = Vt + (size_t)bh * DKH * S_LEN;

  bf16x8 qf[2];
  {
    int qrow = q0 + wid * 16 + c0;
#pragma unroll
    for (int ks = 0; ks < 2; ++ks)
      qf[ks] = *(const bf16x8*)(Qh + (size_t)qrow * DKH + ks * 32 + gi * 8);
  }

  float mrow = -1e30f, lrow = 0.f;
  f32x4 o[4];
#pragma unroll
  for (int i = 0; i < 4; ++i) o[i] = (f32x4){0, 0, 0, 0};

  int rs = t >> 3, uP = t & 7;
  int q_abs = q0 + wid * 16 + c0;

  int c8 = uP ^ (rs & 7);
  const unsigned short* kp0 = Kh + ((size_t)(tile0 * 64 + rs) * DKH) + c8 * 8;
  const unsigned short* kp1 = kp0 + 32 * DKH;
  const unsigned short* vp0 = Vh + (size_t)rs * S_LEN + tile0 * 64 + c8 * 8;
  const unsigned short* vp1 = vp0 + (size_t)32 * S_LEN;
  char* klds0 = kbuf + rs * 128 + uP * 16;
  char* klds1 = klds0 + 32 * 128;
  int vlds_off0 = rs * 128 + uP * 16;

  gload_lds16(kp0, klds0);
  gload_lds16(kp1, klds1);
  gload_lds16(vp0, vbuf[0] + vlds_off0);
  gload_lds16(vp1, vbuf[0] + vlds_off0 + 32 * 128);
  kp0 += 64 * DKH; kp1 += 64 * DKH; vp0 += 64; vp1 += 64;

  for (int tt = 0; tt < nt; ++tt) {
    int tile = tile0 + tt;
    int kv0 = tile << 6;
    __syncthreads();   // staged K(t), V(t) landed

    // S^T = K * Q^T: sc[f][i] = S[q=c0][kv = kv0 + f*16 + gi*4 + i]
    f32x4 sc[4];
#pragma unroll
    for (int f = 0; f < 4; ++f) {
      f32x4 s = (f32x4){0, 0, 0, 0};
#pragma unroll
      for (int ks = 0; ks < 2; ++ks) {
        int rb = f * 16 + c0;
        int uL = ks * 4 + gi;
        bf16x8 kf = *(const bf16x8*)(kbuf + rb * 128 + ((uL ^ (rb & 7)) * 16));
        s = __builtin_amdgcn_mfma_f32_16x16x32_bf16(kf, qf[ks], s, 0, 0, 0);
      }
      sc[f] = s;
    }
    __syncthreads();   // all waves done reading kbuf

    if (tt + 1 < nt) {
      char* vb = vbuf[(tt + 1) & 1];
      gload_lds16(kp0, klds0);
      gload_lds16(kp1, klds1);
      gload_lds16(vp0, vb + vlds_off0);
      gload_lds16(vp1, vb + vlds_off0 + 32 * 128);
      kp0 += 64 * DKH; kp1 += 64 * DKH; vp0 += 64; vp1 += 64;
    }

    if (tile == qt) {
      int kvb = kv0 + gi * 4;
#pragma unroll
      for (int f = 0; f < 4; ++f)
#pragma unroll
        for (int i = 0; i < 4; ++i)
          if (kvb + f * 16 + i > q_abs) sc[f][i] = -1e30f;
    }

    float m01 = fmaxf(fmaxf(sc[0][0], sc[0][1]), fmaxf(sc[0][2], sc[0][3]));
    float m23 = fmaxf(fmaxf(sc[1][0], sc[1][1]), fmaxf(sc[1][2], sc[1][3]));
    float m45 = fmaxf(fmaxf(sc[2][0], sc[2][1]), fmaxf(sc[2][2], sc[2][3]));
    float m67 = fmaxf(fmaxf(sc[3][0], sc[3][1]), fmaxf(sc[3][2], sc[3][3]));
    float tmax = fmaxf(fmaxf(m01, m23), fmaxf(m45, m67));
    tmax = fmaxf(tmax, __shfl_xor(tmax, 16));
    tmax = fmaxf(tmax, __shfl_xor(tmax, 32));

    float alpha = 1.f;
    if (__any(tmax > mrow)) {
      float mnew = fmaxf(mrow, tmax);
      alpha = exp2a(mrow - mnew);
      mrow = mnew;
      float af0 = __shfl(alpha, gi * 4 + 0);
      float af1 = __shfl(alpha, gi * 4 + 1);
      float af2 = __shfl(alpha, gi * 4 + 2);
      float af3 = __shfl(alpha, gi * 4 + 3);
#pragma unroll
      for (int df = 0; df < 4; ++df) {
        o[df][0] *= af0; o[df][1] *= af1; o[df][2] *= af2; o[df][3] *= af3;
      }
    }

    float ps0 = 0, ps1 = 0, ps2 = 0, ps3 = 0;
#pragma unroll
    for (int f = 0; f < 4; ++f) {
      float p0 = exp2a(sc[f][0] - mrow);
      float p1 = exp2a(sc[f][1] - mrow);
      float p2 = exp2a(sc[f][2] - mrow);
      float p3 = exp2a(sc[f][3] - mrow);
      sc[f][0] = p0; sc[f][1] = p1; sc[f][2] = p2; sc[f][3] = p3;
      ps0 += p0; ps1 += p1; ps2 += p2; ps3 += p3;
    }
    float ps = (ps0 + ps1) + (ps2 + ps3);
    ps += __shfl_xor(ps, 16);
    ps += __shfl_xor(ps, 32);
    lrow = lrow * alpha + ps;

    {
      char* pbrow = (char*)&pbuf[wid][0][0] + c0 * 176;
#pragma unroll
      for (int f = 0; f < 4; ++f) {
        unsigned int u0 = cvtpk(sc[f][0], sc[f][1]);
        unsigned int u1 = cvtpk(sc[f][2], sc[f][3]);
        *(unsigned int*)(pbrow + (f * 16 + gi * 4) * 2)     = u0;
        *(unsigned int*)(pbrow + (f * 16 + gi * 4) * 2 + 4) = u1;
      }
    }
    asm volatile("s_waitcnt lgkmcnt(0)" ::: "memory");

    {
      const char* pb = (const char*)&pbuf[wid][0][0] + c0 * 176;
      const char* vcur = vbuf[tt & 1];
#pragma unroll
      for (int ks = 0; ks < 2; ++ks) {
        bf16x8 pa = *(const bf16x8*)(pb + ks * 64 + gi * 16);
#pragma unroll
        for (int df = 0; df < 4; ++df) {
          int rv = df * 16 + c0;
          int uL = ks * 4 + gi;
          bf16x8 vf = *(const bf16x8*)(vcur + rv * 128 + ((uL ^ (rv & 7)) * 16));
          o[df] = __builtin_amdgcn_mfma_f32_16x16x32_bf16(pa, vf, o[df], 0, 0, 0);
        }
      }
    }
  }

  unsigned short* po = pO + (size_t)pid * 4096;
#pragma unroll
  for (int i = 0; i < 4; ++i) {
    int r = wid * 16 + gi * 4 + i;
#pragma unroll
    for (int df = 0; df < 4; ++df)
      po[r * 64 + df * 16 + c0] = f2bf(o[df][i]);
  }
  if (lane < 16) {
    pm[pid * 64 + wid * 16 + c0] = mrow;
    pl[pid * 64 + wid * 16 + c0] = lrow;
  }
}

// ---------------- combine partials -> attn output [B*S, 1024] bf16 ----------
__global__ __launch_bounds__(256) void attn_combine(
    const unsigned short* __restrict__ pO,
    const float* __restrict__ pm,
    const float* __restrict__ pl,
    unsigned short* __restrict__ Out)
{
  int qt = blockIdx.x, bh = blockIdx.y;
  int t = threadIdx.x;
  int r = t >> 2, cseg = (t & 3) * 16;
  int pid0 = bh * 48 + qt;
  bool two = (qt >= 16);
  int pid1 = bh * 48 + 32 + qt - 16;

  float m0 = pm[pid0 * 64 + r];
  float l0 = pl[pid0 * 64 + r];
  float M = m0, w0 = 1.f, w1 = 0.f, l = l0;
  if (two) {
    float m1 = pm[pid1 * 64 + r];
    float l1 = pl[pid1 * 64 + r];
    M = fmaxf(m0, m1);
    w0 = exp2a(m0 - M);
    w1 = exp2a(m1 - M);
    l = w0 * l0 + w1 * l1;
  }
  float rl = 1.0f / l;

  const unsigned short* o0 = pO + (size_t)pid0 * 4096 + r * 64 + cseg;
  const unsigned short* o1 = pO + (size_t)pid1 * 4096 + r * 64 + cseg;
  int b = bh >> 4, h = bh & 15;
  size_t base = ((size_t)(b * S_LEN) + (qt * 64 + r)) * DM + h * DKH + cseg;

  bf16x8 a0 = *(const bf16x8*)o0;
  bf16x8 a1 = *(const bf16x8*)(o0 + 8);
  unsigned short res[16];
  if (two) {
    bf16x8 b0 = *(const bf16x8*)o1;
    bf16x8 b1 = *(const bf16x8*)(o1 + 8);
#pragma unroll
    for (int j = 0; j < 8; ++j) {
      res[j]     = f2bf((w0 * bf2f((unsigned short)a0[j]) + w1 * bf2f((unsigned short)b0[j])) * rl);
      res[j + 8] = f2bf((w0 * bf2f((unsigned short)a1[j]) + w1 * bf2f((unsigned short)b1[j])) * rl);
    }
  } else {
#pragma unroll
    for (int j = 0; j < 8; ++j) {
      res[j]     = f2bf(bf2f((unsigned short)a0[j]) * rl);
      res[j + 8] = f2bf(bf2f((unsigned short)a1[j]) * rl);
    }
  }
  *(u32x4*)(Out + base)     = *(u32x4*)res;
  *(u32x4*)(Out + base + 8) = *(u32x4*)(res + 8);
}

// ----------------------------------------------------------------------------
extern "C" void kernel_launch(void* const* d_in, const int* in_sizes, int n_in,
                              void* d_out, int out_size, void* d_ws, size_t ws_size,
                              hipStream_t stream) {
  const float* x       = (const float*)d_in[0];
  const float* w_atten = (const float*)d_in[1];
  const float* b_atten = (const float*)d_in[2];
  const float* w_proj  = (const float*)d_in[3];
  const float* b_proj  = (const float*)d_in[4];
  float* out = (float*)d_out;
  char* ws = (char*)d_ws;

  unsigned short* x_bf  = (unsigned short*)(ws);
  unsigned short* wa_bf = (unsigned short*)(ws + ((size_t)8  << 20));
  unsigned short* wp_bf = (unsigned short*)(ws + ((size_t)14 << 20));
  unsigned short* q_bf  = (unsigned short*)(ws + ((size_t)16 << 20));
  unsigned short* k_bf  = (unsigned short*)(ws + ((size_t)24 << 20));
  unsigned short* vt_bf = (unsigned short*)(ws + ((size_t)32 << 20));
  unsigned short* at_bf = (unsigned short*)(ws + ((size_t)40 << 20));
  // partial buffers overlay x_bf/wa_bf (dead after gemm0)
  unsigned short* pO = (unsigned short*)(ws);
  float* pm = (float*)(ws + 12582912);
  float* pl = (float*)(ws + 12976128);

  cvt_f32_to_bf16<<<2048, 256, 0, stream>>>(x, x_bf, 4194304);
  cvt_f32_to_bf16<<<1536, 256, 0, stream>>>(w_atten, wa_bf, 3145728);
  cvt_f32_to_bf16<<<512, 256, 0, stream>>>(w_proj, wp_bf, 1048576);

  gemm256<0><<<dim3(12, 16), 512, 0, stream>>>(x_bf, wa_bf, b_atten, nullptr,
                                               q_bf, k_bf, vt_bf, 4096, 3072, 1024);
  attn_part<<<dim3(48, 32), 256, 0, stream>>>(q_bf, k_bf, vt_bf, pO, pm, pl);
  attn_combine<<<dim3(32, 32), 256, 0, stream>>>(pO, pm, pl, at_bf);
  gemm256<1><<<dim3(4, 16), 512, 0, stream>>>(at_bf, wp_bf, b_proj, out,
                                              nullptr, nullptr, nullptr, 4096, 1024, 1024);
}

// Round 6
// 165.490 us; speedup vs baseline: 1.0218x; 1.0218x over previous
//
#include <hip/hip_runtime.h>
#include <hip/hip_bf16.h>

#define S_LEN 2048
#define NH 16
#define DKH 64
#define DM 1024
// 1/sqrt(64) * log2(e): folded into Q at the QKV-GEMM epilogue
#define QK_SCALE_L2E 0.1803368801111244f

typedef __attribute__((ext_vector_type(8))) short bf16x8;
typedef __attribute__((ext_vector_type(4))) float f32x4;
typedef __attribute__((ext_vector_type(4))) unsigned int u32x4;

__device__ __forceinline__ unsigned short f2bf(float f) {
  unsigned int x = __builtin_bit_cast(unsigned int, f);
  x += 0x7fffu + ((x >> 16) & 1u);   // RNE
  return (unsigned short)(x >> 16);
}
__device__ __forceinline__ float bf2f(unsigned short u) {
  unsigned int x = ((unsigned int)u) << 16;
  return __builtin_bit_cast(float, x);
}
// hardware exp2 (1 TRANS op; denorm-flush fine for softmax)
__device__ __forceinline__ float exp2a(float x) {
  float r; asm("v_exp_f32 %0, %1" : "=v"(r) : "v"(x)); return r;
}
// pack 2 fp32 -> 2 bf16 in one op: D.lo = a, D.hi = b
__device__ __forceinline__ unsigned int cvtpk(float a, float b) {
  unsigned int r; asm("v_cvt_pk_bf16_f32 %0, %1, %2" : "=v"(r) : "v"(a), "v"(b)); return r;
}

__device__ __forceinline__ void gload_lds16(const void* g, void* l) {
  __builtin_amdgcn_global_load_lds(
      (const __attribute__((address_space(1))) unsigned int*)g,
      (__attribute__((address_space(3))) unsigned int*)l, 16, 0, 0);
}

// ---------------- fp32 -> bf16 conversion (memory-bound pre-pass) -----------
__global__ void cvt_f32_to_bf16(const float* __restrict__ in,
                                unsigned short* __restrict__ out, int n) {
  int i = (blockIdx.x * blockDim.x + threadIdx.x) * 8;
  if (i >= n) return;
  float4 a = *(const float4*)(in + i);
  float4 b = *(const float4*)(in + i + 4);
  union { unsigned short us[8]; u32x4 v; } r;
  r.us[0] = f2bf(a.x); r.us[1] = f2bf(a.y); r.us[2] = f2bf(a.z); r.us[3] = f2bf(a.w);
  r.us[4] = f2bf(b.x); r.us[5] = f2bf(b.y); r.us[6] = f2bf(b.z); r.us[7] = f2bf(b.w);
  *(u32x4*)(out + i) = r.v;
}

// ---------------- 256x256 bf16 GEMM, C = A * B^T, BK=64, 8 waves, T4 --------
// m201 geometry: 128KB LDS double-buffer (2 slots x [A 32KB + B 32KB]).
// Counted vmcnt: STAGE(next) stays IN FLIGHT across compute + barriers;
// top barrier waits vmcnt(8) (current tile resident, next 8 loads pending),
// bottom barrier waits lgkmcnt(0) only (never drains vmcnt).
// LDS row = 64 bf16 = 128B; same XOR swizzle as verified R4 kernel (0 confl).
template<int MODE>
__global__ __launch_bounds__(512, 2) void gemm256(
    const unsigned short* __restrict__ A,   // [M,K] bf16 row-major
    const unsigned short* __restrict__ Bt,  // [N,K] bf16 row-major
    const float* __restrict__ bias,         // [N]
    float* __restrict__ Cf,                 // MODE 1
    unsigned short* __restrict__ qo,        // MODE 0
    unsigned short* __restrict__ ko,
    unsigned short* __restrict__ vto,
    int M, int N, int K)
{
  __shared__ __align__(16) char As[2][256 * 128];   // 32KB per slot
  __shared__ __align__(16) char Bs[2][256 * 128];
  int t = threadIdx.x;
  int lane = t & 63, wid = t >> 6;
  int wr = wid >> 2, wc = wid & 3;         // 2(M) x 4(N) waves
  int m0 = blockIdx.y << 8, n0 = blockIdx.x << 8;
  int gi = lane >> 4, c0 = lane & 15;
  int rs = t >> 3, uP = t & 7;

  f32x4 acc[8][4];
#pragma unroll
  for (int m = 0; m < 8; ++m)
#pragma unroll
    for (int n = 0; n < 4; ++n) acc[m][n] = (f32x4){0.f, 0.f, 0.f, 0.f};

  // staging: thread covers rows rs+{0,64,128,192} for A and B (8 loads/step).
  // (rs + it*64) & 7 == rs & 7, so the swizzled chunk is constant.
  int c8 = (uP ^ (rs & 7)) * 8;
  const unsigned short *ap0, *ap1, *ap2, *ap3, *bp0, *bp1, *bp2, *bp3;
  ap0 = A  + (size_t)(m0 + rs)       * K + c8;
  ap1 = A  + (size_t)(m0 + rs + 64)  * K + c8;
  ap2 = A  + (size_t)(m0 + rs + 128) * K + c8;
  ap3 = A  + (size_t)(m0 + rs + 192) * K + c8;
  bp0 = Bt + (size_t)(n0 + rs)       * K + c8;
  bp1 = Bt + (size_t)(n0 + rs + 64)  * K + c8;
  bp2 = Bt + (size_t)(n0 + rs + 128) * K + c8;
  bp3 = Bt + (size_t)(n0 + rs + 192) * K + c8;
  int l0 = rs * 128 + uP * 16;
  int l1 = l0 + 64 * 128, l2 = l0 + 128 * 128, l3 = l0 + 192 * 128;

#define STAGE(slot)                                                  \
  do {                                                               \
    gload_lds16(ap0, As[slot] + l0); gload_lds16(ap1, As[slot] + l1);\
    gload_lds16(ap2, As[slot] + l2); gload_lds16(ap3, As[slot] + l3);\
    gload_lds16(bp0, Bs[slot] + l0); gload_lds16(bp1, Bs[slot] + l1);\
    gload_lds16(bp2, Bs[slot] + l2); gload_lds16(bp3, Bs[slot] + l3);\
    ap0 += 64; ap1 += 64; ap2 += 64; ap3 += 64;                      \
    bp0 += 64; bp1 += 64; bp2 += 64; bp3 += 64;                      \
  } while (0)

  const int NT = K >> 6;
  STAGE(0);
  for (int kt = 0; kt < NT; ++kt) {
    int cur = kt & 1;
    if (kt + 1 < NT) {
      STAGE(cur ^ 1);                     // 8 loads in flight across this step
      asm volatile("s_waitcnt vmcnt(8)" ::: "memory");  // tile kt resident
    } else {
      asm volatile("s_waitcnt vmcnt(0)" ::: "memory");
    }
    asm volatile("s_barrier" ::: "memory");

#pragma unroll
    for (int kk = 0; kk < 2; ++kk) {
      int uL = kk * 4 + gi;
      bf16x8 bfr[4], af[8];
#pragma unroll
      for (int n = 0; n < 4; ++n) {
        int rb = wc * 64 + n * 16 + c0;
        bfr[n] = *(const bf16x8*)(Bs[cur] + rb * 128 + ((uL ^ (rb & 7)) * 16));
      }
#pragma unroll
      for (int m = 0; m < 8; ++m) {
        int ra = wr * 128 + m * 16 + c0;
        af[m] = *(const bf16x8*)(As[cur] + ra * 128 + ((uL ^ (ra & 7)) * 16));
      }
#pragma unroll
      for (int m = 0; m < 8; ++m)
#pragma unroll
        for (int n = 0; n < 4; ++n)
          acc[m][n] = __builtin_amdgcn_mfma_f32_16x16x32_bf16(af[m], bfr[n], acc[m][n], 0, 0, 0);
    }
    // my ds_reads of slot cur complete; sync before next STAGE overwrites it.
    asm volatile("s_waitcnt lgkmcnt(0)\n\ts_barrier" ::: "memory");
  }
#undef STAGE

  float bias_v[4];
#pragma unroll
  for (int n = 0; n < 4; ++n) bias_v[n] = bias[n0 + wc * 64 + n * 16 + c0];

#pragma unroll
  for (int m = 0; m < 8; ++m) {
#pragma unroll
    for (int n = 0; n < 4; ++n) {
#pragma unroll
      for (int rI = 0; rI < 4; ++rI) {
        int mm = m0 + wr * 128 + m * 16 + gi * 4 + rI;
        int nn = n0 + wc * 64 + n * 16 + c0;
        float v = acc[m][n][rI] + bias_v[n];
        if (MODE == 1) {
          Cf[(size_t)mm * N + nn] = v;
        } else {
          int b = mm >> 11, s = mm & 2047;
          int which = nn >> 10, w2 = nn & 1023;
          int h = w2 >> 6, dk = w2 & 63;
          size_t hoff = (size_t)(b * NH + h);
          if (which == 0) {
            qo[(hoff * S_LEN + s) * DKH + dk] = f2bf(v * QK_SCALE_L2E);
          } else if (which == 1) {
            ko[(hoff * S_LEN + s) * DKH + dk] = f2bf(v);
          } else {
            vto[(hoff * DKH + dk) * S_LEN + s] = f2bf(v);  // V transposed
          }
        }
      }
    }
  }
}

// ---------------- split-KV flash attention work table (LPT order) -----------
struct WorkItem { unsigned char qt, t0, nt; };
__device__ __constant__ WorkItem g_items[48] = {
  {15,0,16},
  {16,0,16},{17,0,16},{18,0,16},{19,0,16},{20,0,16},{21,0,16},{22,0,16},{23,0,16},
  {24,0,16},{25,0,16},{26,0,16},{27,0,16},{28,0,16},{29,0,16},{30,0,16},{31,0,16},
  {31,16,16},
  {14,0,15},{30,16,15},
  {13,0,14},{29,16,14},
  {12,0,13},{28,16,13},
  {11,0,12},{27,16,12},
  {10,0,11},{26,16,11},
  { 9,0,10},{25,16,10},
  { 8,0, 9},{24,16, 9},
  { 7,0, 8},{23,16, 8},
  { 6,0, 7},{22,16, 7},
  { 5,0, 6},{21,16, 6},
  { 4,0, 5},{20,16, 5},
  { 3,0, 4},{19,16, 4},
  { 2,0, 3},{18,16, 3},
  { 1,0, 2},{17,16, 2},
  { 0,0, 1},{16,16, 1},
};

// ---------------- flash attention (partial), swapped-QK^T in-reg softmax ----
__global__ __launch_bounds__(256) void attn_part(
    const unsigned short* __restrict__ Q,   // [BH, S, 64] bf16, pre-scaled
    const unsigned short* __restrict__ Kb,  // [BH, S, 64] bf16
    const unsigned short* __restrict__ Vt,  // [BH, 64, S] bf16
    unsigned short* __restrict__ pO,        // [1536][64][64] bf16
    float* __restrict__ pm,                 // [1536][64]
    float* __restrict__ pl)                 // [1536][64]
{
  __shared__ __align__(16) char kbuf[64 * 128];
  __shared__ __align__(16) char vbuf[2][64 * 128];
  __shared__ __align__(16) unsigned short pbuf[4][16][88];  // 176B rows
  int t = threadIdx.x;
  int lane = t & 63, wid = t >> 6;
  int gi = lane >> 4, c0 = lane & 15;
  WorkItem wi = g_items[blockIdx.x];
  int bh = blockIdx.y;
  int qt = wi.qt, tile0 = wi.t0, nt = wi.nt;
  int pid = bh * 48 + (tile0 ? (32 + qt - 16) : qt);
  int q0 = qt << 6;
  const unsigned short* Qh = Q  + (size_t)bh * S_LEN * DKH;
  const unsigned short* Kh = Kb + (size_t)bh * S_LEN * DKH;
  const unsigned short* Vh = Vt + (size_t)bh * DKH * S_LEN;

  bf16x8 qf[2];
  {
    int qrow = q0 + wid * 16 + c0;
#pragma unroll
    for (int ks = 0; ks < 2; ++ks)
      qf[ks] = *(const bf16x8*)(Qh + (size_t)qrow * DKH + ks * 32 + gi * 8);
  }

  float mrow = -1e30f, lrow = 0.f;
  f32x4 o[4];
#pragma unroll
  for (int i = 0; i < 4; ++i) o[i] = (f32x4){0, 0, 0, 0};

  int rs = t >> 3, uP = t & 7;
  int q_abs = q0 + wid * 16 + c0;

  int c8 = uP ^ (rs & 7);
  const unsigned short* kp0 = Kh + ((size_t)(tile0 * 64 + rs) * DKH) + c8 * 8;
  const unsigned short* kp1 = kp0 + 32 * DKH;
  const unsigned short* vp0 = Vh + (size_t)rs * S_LEN + tile0 * 64 + c8 * 8;
  const unsigned short* vp1 = vp0 + (size_t)32 * S_LEN;
  char* klds0 = kbuf + rs * 128 + uP * 16;
  char* klds1 = klds0 + 32 * 128;
  int vlds_off0 = rs * 128 + uP * 16;

  gload_lds16(kp0, klds0);
  gload_lds16(kp1, klds1);
  gload_lds16(vp0, vbuf[0] + vlds_off0);
  gload_lds16(vp1, vbuf[0] + vlds_off0 + 32 * 128);
  kp0 += 64 * DKH; kp1 += 64 * DKH; vp0 += 64; vp1 += 64;

  for (int tt = 0; tt < nt; ++tt) {
    int tile = tile0 + tt;
    int kv0 = tile << 6;
    __syncthreads();   // staged K(t), V(t) landed

    // S^T = K * Q^T: sc[f][i] = S[q=c0][kv = kv0 + f*16 + gi*4 + i]
    f32x4 sc[4];
#pragma unroll
    for (int f = 0; f < 4; ++f) {
      f32x4 s = (f32x4){0, 0, 0, 0};
#pragma unroll
      for (int ks = 0; ks < 2; ++ks) {
        int rb = f * 16 + c0;
        int uL = ks * 4 + gi;
        bf16x8 kf = *(const bf16x8*)(kbuf + rb * 128 + ((uL ^ (rb & 7)) * 16));
        s = __builtin_amdgcn_mfma_f32_16x16x32_bf16(kf, qf[ks], s, 0, 0, 0);
      }
      sc[f] = s;
    }
    __syncthreads();   // all waves done reading kbuf

    if (tt + 1 < nt) {
      char* vb = vbuf[(tt + 1) & 1];
      gload_lds16(kp0, klds0);
      gload_lds16(kp1, klds1);
      gload_lds16(vp0, vb + vlds_off0);
      gload_lds16(vp1, vb + vlds_off0 + 32 * 128);
      kp0 += 64 * DKH; kp1 += 64 * DKH; vp0 += 64; vp1 += 64;
    }

    if (tile == qt) {
      int kvb = kv0 + gi * 4;
#pragma unroll
      for (int f = 0; f < 4; ++f)
#pragma unroll
        for (int i = 0; i < 4; ++i)
          if (kvb + f * 16 + i > q_abs) sc[f][i] = -1e30f;
    }

    float m01 = fmaxf(fmaxf(sc[0][0], sc[0][1]), fmaxf(sc[0][2], sc[0][3]));
    float m23 = fmaxf(fmaxf(sc[1][0], sc[1][1]), fmaxf(sc[1][2], sc[1][3]));
    float m45 = fmaxf(fmaxf(sc[2][0], sc[2][1]), fmaxf(sc[2][2], sc[2][3]));
    float m67 = fmaxf(fmaxf(sc[3][0], sc[3][1]), fmaxf(sc[3][2], sc[3][3]));
    float tmax = fmaxf(fmaxf(m01, m23), fmaxf(m45, m67));
    tmax = fmaxf(tmax, __shfl_xor(tmax, 16));
    tmax = fmaxf(tmax, __shfl_xor(tmax, 32));

    float alpha = 1.f;
    if (__any(tmax > mrow)) {
      float mnew = fmaxf(mrow, tmax);
      alpha = exp2a(mrow - mnew);
      mrow = mnew;
      float af0 = __shfl(alpha, gi * 4 + 0);
      float af1 = __shfl(alpha, gi * 4 + 1);
      float af2 = __shfl(alpha, gi * 4 + 2);
      float af3 = __shfl(alpha, gi * 4 + 3);
#pragma unroll
      for (int df = 0; df < 4; ++df) {
        o[df][0] *= af0; o[df][1] *= af1; o[df][2] *= af2; o[df][3] *= af3;
      }
    }

    float ps0 = 0, ps1 = 0, ps2 = 0, ps3 = 0;
#pragma unroll
    for (int f = 0; f < 4; ++f) {
      float p0 = exp2a(sc[f][0] - mrow);
      float p1 = exp2a(sc[f][1] - mrow);
      float p2 = exp2a(sc[f][2] - mrow);
      float p3 = exp2a(sc[f][3] - mrow);
      sc[f][0] = p0; sc[f][1] = p1; sc[f][2] = p2; sc[f][3] = p3;
      ps0 += p0; ps1 += p1; ps2 += p2; ps3 += p3;
    }
    float ps = (ps0 + ps1) + (ps2 + ps3);
    ps += __shfl_xor(ps, 16);
    ps += __shfl_xor(ps, 32);
    lrow = lrow * alpha + ps;

    {
      char* pbrow = (char*)&pbuf[wid][0][0] + c0 * 176;
#pragma unroll
      for (int f = 0; f < 4; ++f) {
        unsigned int u0 = cvtpk(sc[f][0], sc[f][1]);
        unsigned int u1 = cvtpk(sc[f][2], sc[f][3]);
        *(unsigned int*)(pbrow + (f * 16 + gi * 4) * 2)     = u0;
        *(unsigned int*)(pbrow + (f * 16 + gi * 4) * 2 + 4) = u1;
      }
    }
    asm volatile("s_waitcnt lgkmcnt(0)" ::: "memory");

    {
      const char* pb = (const char*)&pbuf[wid][0][0] + c0 * 176;
      const char* vcur = vbuf[tt & 1];
#pragma unroll
      for (int ks = 0; ks < 2; ++ks) {
        bf16x8 pa = *(const bf16x8*)(pb + ks * 64 + gi * 16);
#pragma unroll
        for (int df = 0; df < 4; ++df) {
          int rv = df * 16 + c0;
          int uL = ks * 4 + gi;
          bf16x8 vf = *(const bf16x8*)(vcur + rv * 128 + ((uL ^ (rv & 7)) * 16));
          o[df] = __builtin_amdgcn_mfma_f32_16x16x32_bf16(pa, vf, o[df], 0, 0, 0);
        }
      }
    }
  }

  unsigned short* po = pO + (size_t)pid * 4096;
#pragma unroll
  for (int i = 0; i < 4; ++i) {
    int r = wid * 16 + gi * 4 + i;
#pragma unroll
    for (int df = 0; df < 4; ++df)
      po[r * 64 + df * 16 + c0] = f2bf(o[df][i]);
  }
  if (lane < 16) {
    pm[pid * 64 + wid * 16 + c0] = mrow;
    pl[pid * 64 + wid * 16 + c0] = lrow;
  }
}

// ---------------- combine partials -> attn output [B*S, 1024] bf16 ----------
__global__ __launch_bounds__(256) void attn_combine(
    const unsigned short* __restrict__ pO,
    const float* __restrict__ pm,
    const float* __restrict__ pl,
    unsigned short* __restrict__ Out)
{
  int qt = blockIdx.x, bh = blockIdx.y;
  int t = threadIdx.x;
  int r = t >> 2, cseg = (t & 3) * 16;
  int pid0 = bh * 48 + qt;
  bool two = (qt >= 16);
  int pid1 = bh * 48 + 32 + qt - 16;

  float m0 = pm[pid0 * 64 + r];
  float l0 = pl[pid0 * 64 + r];
  float M = m0, w0 = 1.f, w1 = 0.f, l = l0;
  if (two) {
    float m1 = pm[pid1 * 64 + r];
    float l1 = pl[pid1 * 64 + r];
    M = fmaxf(m0, m1);
    w0 = exp2a(m0 - M);
    w1 = exp2a(m1 - M);
    l = w0 * l0 + w1 * l1;
  }
  float rl = 1.0f / l;

  const unsigned short* o0 = pO + (size_t)pid0 * 4096 + r * 64 + cseg;
  const unsigned short* o1 = pO + (size_t)pid1 * 4096 + r * 64 + cseg;
  int b = bh >> 4, h = bh & 15;
  size_t base = ((size_t)(b * S_LEN) + (qt * 64 + r)) * DM + h * DKH + cseg;

  bf16x8 a0 = *(const bf16x8*)o0;
  bf16x8 a1 = *(const bf16x8*)(o0 + 8);
  unsigned short res[16];
  if (two) {
    bf16x8 b0 = *(const bf16x8*)o1;
    bf16x8 b1 = *(const bf16x8*)(o1 + 8);
#pragma unroll
    for (int j = 0; j < 8; ++j) {
      res[j]     = f2bf((w0 * bf2f((unsigned short)a0[j]) + w1 * bf2f((unsigned short)b0[j])) * rl);
      res[j + 8] = f2bf((w0 * bf2f((unsigned short)a1[j]) + w1 * bf2f((unsigned short)b1[j])) * rl);
    }
  } else {
#pragma unroll
    for (int j = 0; j < 8; ++j) {
      res[j]     = f2bf(bf2f((unsigned short)a0[j]) * rl);
      res[j + 8] = f2bf(bf2f((unsigned short)a1[j]) * rl);
    }
  }
  *(u32x4*)(Out + base)     = *(u32x4*)res;
  *(u32x4*)(Out + base + 8) = *(u32x4*)(res + 8);
}

// ----------------------------------------------------------------------------
extern "C" void kernel_launch(void* const* d_in, const int* in_sizes, int n_in,
                              void* d_out, int out_size, void* d_ws, size_t ws_size,
                              hipStream_t stream) {
  const float* x       = (const float*)d_in[0];
  const float* w_atten = (const float*)d_in[1];
  const float* b_atten = (const float*)d_in[2];
  const float* w_proj  = (const float*)d_in[3];
  const float* b_proj  = (const float*)d_in[4];
  float* out = (float*)d_out;
  char* ws = (char*)d_ws;

  unsigned short* x_bf  = (unsigned short*)(ws);
  unsigned short* wa_bf = (unsigned short*)(ws + ((size_t)8  << 20));
  unsigned short* wp_bf = (unsigned short*)(ws + ((size_t)14 << 20));
  unsigned short* q_bf  = (unsigned short*)(ws + ((size_t)16 << 20));
  unsigned short* k_bf  = (unsigned short*)(ws + ((size_t)24 << 20));
  unsigned short* vt_bf = (unsigned short*)(ws + ((size_t)32 << 20));
  unsigned short* at_bf = (unsigned short*)(ws + ((size_t)40 << 20));
  // partial buffers overlay x_bf/wa_bf (dead after gemm0)
  unsigned short* pO = (unsigned short*)(ws);
  float* pm = (float*)(ws + 12582912);
  float* pl = (float*)(ws + 12976128);

  cvt_f32_to_bf16<<<2048, 256, 0, stream>>>(x, x_bf, 4194304);
  cvt_f32_to_bf16<<<1536, 256, 0, stream>>>(w_atten, wa_bf, 3145728);
  cvt_f32_to_bf16<<<512, 256, 0, stream>>>(w_proj, wp_bf, 1048576);

  gemm256<0><<<dim3(12, 16), 512, 0, stream>>>(x_bf, wa_bf, b_atten, nullptr,
                                               q_bf, k_bf, vt_bf, 4096, 3072, 1024);
  attn_part<<<dim3(48, 32), 256, 0, stream>>>(q_bf, k_bf, vt_bf, pO, pm, pl);
  attn_combine<<<dim3(32, 32), 256, 0, stream>>>(pO, pm, pl, at_bf);
  gemm256<1><<<dim3(4, 16), 512, 0, stream>>>(at_bf, wp_bf, b_proj, out,
                                              nullptr, nullptr, nullptr, 4096, 1024, 1024);
}

// Round 7
// 158.079 us; speedup vs baseline: 1.0697x; 1.0469x over previous
//
#include <hip/hip_runtime.h>
#include <hip/hip_bf16.h>

#define S_LEN 2048
#define NH 16
#define DKH 64
#define DM 1024
// 1/sqrt(64) * log2(e): folded into Q at the QKV-GEMM epilogue
#define QK_SCALE_L2E 0.1803368801111244f

typedef __attribute__((ext_vector_type(8))) short bf16x8;
typedef __attribute__((ext_vector_type(4))) float f32x4;
typedef __attribute__((ext_vector_type(4))) unsigned int u32x4;

__device__ __forceinline__ unsigned short f2bf(float f) {
  unsigned int x = __builtin_bit_cast(unsigned int, f);
  x += 0x7fffu + ((x >> 16) & 1u);   // RNE
  return (unsigned short)(x >> 16);
}
__device__ __forceinline__ float bf2f(unsigned short u) {
  unsigned int x = ((unsigned int)u) << 16;
  return __builtin_bit_cast(float, x);
}
__device__ __forceinline__ float exp2a(float x) {
  float r; asm("v_exp_f32 %0, %1" : "=v"(r) : "v"(x)); return r;
}
__device__ __forceinline__ unsigned int cvtpk(float a, float b) {
  unsigned int r; asm("v_cvt_pk_bf16_f32 %0, %1, %2" : "=v"(r) : "v"(a), "v"(b)); return r;
}

__device__ __forceinline__ void gload_lds16(const void* g, void* l) {
  __builtin_amdgcn_global_load_lds(
      (const __attribute__((address_space(1))) unsigned int*)g,
      (__attribute__((address_space(3))) unsigned int*)l, 16, 0, 0);
}

// ---------------- fp32 -> bf16 conversion (memory-bound pre-pass) -----------
__global__ void cvt_f32_to_bf16(const float* __restrict__ in,
                                unsigned short* __restrict__ out, int n) {
  int i = (blockIdx.x * blockDim.x + threadIdx.x) * 8;
  if (i >= n) return;
  float4 a = *(const float4*)(in + i);
  float4 b = *(const float4*)(in + i + 4);
  union { unsigned short us[8]; u32x4 v; } r;
  r.us[0] = f2bf(a.x); r.us[1] = f2bf(a.y); r.us[2] = f2bf(a.z); r.us[3] = f2bf(a.w);
  r.us[4] = f2bf(b.x); r.us[5] = f2bf(b.y); r.us[6] = f2bf(b.z); r.us[7] = f2bf(b.w);
  *(u32x4*)(out + i) = r.v;
}

// ============ 256x256 bf16 GEMM, 4-phase counted-vmcnt pipeline =============
// BK=64, 8 waves (2M x 4N), LDS 128KB (2 K-tile slots x [A 32KB + B 32KB]).
// Per K-tile: 4 phases, each = {vmcnt(N); barrier; ds_read quadrant; setprio1;
// 16 MFMA; setprio0; issue next-tile stage unit}. Stage units per tile:
// B(4 loads) -> Aq0,Aq1(2) -> Aq2,Aq3(2). Waits N={3,6,7,8} guarantee the
// consumed unit was issued >=3 phases earlier; loop never drains vmcnt.
// Aq(p) = A rows {32p..32p+31} u {128+32p..128+32p+31} (what phase p reads).
#define ISSUE_B(ns)                                                          \
  do {                                                                       \
    gload_lds16(bq0, Bs[ns] + lb0); gload_lds16(bq1, Bs[ns] + lb1);          \
    gload_lds16(bq2, Bs[ns] + lb2); gload_lds16(bq3, Bs[ns] + lb3);          \
    bq0 += 64; bq1 += 64; bq2 += 64; bq3 += 64;                              \
  } while (0)
#define ISSUE_A01(ns)                                                        \
  do {                                                                       \
    gload_lds16(aq0, As[ns] + la0); gload_lds16(aq1, As[ns] + la1);          \
    aq0 += 64; aq1 += 64;                                                    \
  } while (0)
#define ISSUE_A23(ns)                                                        \
  do {                                                                       \
    gload_lds16(aq2, As[ns] + la2); gload_lds16(aq3, As[ns] + la3);          \
    aq2 += 64; aq3 += 64;                                                    \
  } while (0)

#define PHASE(P, CUR, WN, ISSUE_STMT)                                        \
  do {                                                                       \
    asm volatile("s_waitcnt vmcnt(" #WN ")" ::: "memory");                   \
    __builtin_amdgcn_s_barrier();                                            \
    _Pragma("unroll")                                                        \
    for (int kk = 0; kk < 2; ++kk) {                                         \
      int uL = kk * 4 + gi;                                                  \
      bf16x8 bfr[4], af[2];                                                  \
      _Pragma("unroll")                                                      \
      for (int n = 0; n < 4; ++n) {                                          \
        int rb = wc * 64 + n * 16 + c0;                                      \
        bfr[n] = *(const bf16x8*)(Bs[CUR] + rb * 128 + ((uL ^ (rb & 7)) * 16)); \
      }                                                                      \
      _Pragma("unroll")                                                      \
      for (int j = 0; j < 2; ++j) {                                          \
        int ra = wr * 128 + (2 * (P) + j) * 16 + c0;                         \
        af[j] = *(const bf16x8*)(As[CUR] + ra * 128 + ((uL ^ (ra & 7)) * 16)); \
      }                                                                      \
      __builtin_amdgcn_s_setprio(1);                                         \
      _Pragma("unroll")                                                      \
      for (int j = 0; j < 2; ++j)                                            \
        _Pragma("unroll")                                                    \
        for (int n = 0; n < 4; ++n)                                          \
          acc[2 * (P) + j][n] = __builtin_amdgcn_mfma_f32_16x16x32_bf16(     \
              af[j], bfr[n], acc[2 * (P) + j][n], 0, 0, 0);                  \
      __builtin_amdgcn_s_setprio(0);                                         \
    }                                                                        \
    ISSUE_STMT;                                                              \
  } while (0)

template<int MODE>
__global__ __launch_bounds__(512) void gemm4p(
    const unsigned short* __restrict__ A,   // [M,K] bf16 row-major
    const unsigned short* __restrict__ Bt,  // [N,K] bf16 row-major
    const float* __restrict__ bias,         // [N]
    float* __restrict__ Cf,                 // MODE 1
    unsigned short* __restrict__ qo,        // MODE 0
    unsigned short* __restrict__ ko,
    unsigned short* __restrict__ vto,
    int M, int N, int K)
{
  __shared__ __align__(16) char As[2][32768];
  __shared__ __align__(16) char Bs[2][32768];
  int t = threadIdx.x;
  int lane = t & 63, wid = t >> 6;
  int wr = wid >> 2, wc = wid & 3;          // 2(M) x 4(N) waves
  int m0 = blockIdx.y << 8, n0 = blockIdx.x << 8;
  int gi = lane >> 4, c0 = lane & 15;
  int rq = t >> 3, uP = t & 7;
  int c8 = (uP ^ (rq & 7)) * 8;             // pre-swizzled global col chunk

  f32x4 acc[8][4];
#pragma unroll
  for (int m = 0; m < 8; ++m)
#pragma unroll
    for (int n = 0; n < 4; ++n) acc[m][n] = (f32x4){0.f, 0.f, 0.f, 0.f};

  // A-quadrant staging rows: ar0 + 32p covers {32p..32p+31} u {128+32p..+31}
  int ar0 = (rq < 32) ? rq : rq + 96;
  const unsigned short* aq0 = A + (size_t)(m0 + ar0) * K + c8;
  const unsigned short* aq1 = A + (size_t)(m0 + ar0 + 32) * K + c8;
  const unsigned short* aq2 = A + (size_t)(m0 + ar0 + 64) * K + c8;
  const unsigned short* aq3 = A + (size_t)(m0 + ar0 + 96) * K + c8;
  const unsigned short* bq0 = Bt + (size_t)(n0 + rq) * K + c8;
  const unsigned short* bq1 = Bt + (size_t)(n0 + rq + 64) * K + c8;
  const unsigned short* bq2 = Bt + (size_t)(n0 + rq + 128) * K + c8;
  const unsigned short* bq3 = Bt + (size_t)(n0 + rq + 192) * K + c8;
  int la0 = ar0 * 128 + uP * 16;
  int la1 = la0 + 32 * 128, la2 = la0 + 64 * 128, la3 = la0 + 96 * 128;
  int lb0 = rq * 128 + uP * 16;
  int lb1 = lb0 + 64 * 128, lb2 = lb0 + 128 * 128, lb3 = lb0 + 192 * 128;

  const int NT = K >> 6;
  // prologue: tile 0, issue order B(4), Aq0, Aq1, Aq2, Aq3 (= steady order)
  ISSUE_B(0); ISSUE_A01(0); ISSUE_A23(0);

  for (int kt = 0; kt < NT - 1; ++kt) {
    int cur = kt & 1, ns = cur ^ 1;
    PHASE(0, cur, 3, ISSUE_B(ns));     // oldest 5 landed: B(4)+Aq0
    PHASE(1, cur, 6, ISSUE_A01(ns));   // Aq1 landed (allow Aq2,3 + 4 new)
    PHASE(2, cur, 7, ISSUE_A23(ns));   // Aq2 landed (allow Aq3 + 6 new)
    PHASE(3, cur, 8, (void)0);         // Aq3 landed (allow 8 new)
  }
  { // last tile: no issues, drain progressively
    int cur = (NT - 1) & 1;
    PHASE(0, cur, 3, (void)0);
    PHASE(1, cur, 2, (void)0);
    PHASE(2, cur, 1, (void)0);
    PHASE(3, cur, 0, (void)0);
  }

  float bias_v[4];
#pragma unroll
  for (int n = 0; n < 4; ++n) bias_v[n] = bias[n0 + wc * 64 + n * 16 + c0];

#pragma unroll
  for (int m = 0; m < 8; ++m) {
#pragma unroll
    for (int n = 0; n < 4; ++n) {
#pragma unroll
      for (int rI = 0; rI < 4; ++rI) {
        int mm = m0 + wr * 128 + m * 16 + gi * 4 + rI;
        int nn = n0 + wc * 64 + n * 16 + c0;
        float v = acc[m][n][rI] + bias_v[n];
        if (MODE == 1) {
          Cf[(size_t)mm * N + nn] = v;
        } else {
          int b = mm >> 11, s = mm & 2047;
          int which = nn >> 10, w2 = nn & 1023;
          int h = w2 >> 6, dk = w2 & 63;
          size_t hoff = (size_t)(b * NH + h);
          if (which == 0) {
            qo[(hoff * S_LEN + s) * DKH + dk] = f2bf(v * QK_SCALE_L2E);
          } else if (which == 1) {
            ko[(hoff * S_LEN + s) * DKH + dk] = f2bf(v);
          } else {
            vto[(hoff * DKH + dk) * S_LEN + s] = f2bf(v);  // V transposed
          }
        }
      }
    }
  }
}

// ---------------- 128x128 bf16 GEMM (R4-verified m97 structure) -------------
// Used for proj: grid (8,32)=256 blocks -> full machine, 3-4 blocks/CU TLP.
template<int MODE>
__global__ __launch_bounds__(256) void gemm_bt(
    const unsigned short* __restrict__ A,
    const unsigned short* __restrict__ Bt,
    const float* __restrict__ bias,
    float* __restrict__ Cf,
    unsigned short* __restrict__ qo,
    unsigned short* __restrict__ ko,
    unsigned short* __restrict__ vto,
    int M, int N, int K)
{
  __shared__ __align__(16) char Asm[128 * 128];
  __shared__ __align__(16) char Bsm[128 * 128];
  int t = threadIdx.x;
  int lane = t & 63, wid = t >> 6;
  int wr = wid >> 1, wc = wid & 1;
  int m0 = blockIdx.y << 7, n0 = blockIdx.x << 7;
  int gi = lane >> 4, c0 = lane & 15;
  int rs = t >> 3, uP = t & 7;

  f32x4 acc[4][4];
#pragma unroll
  for (int i = 0; i < 4; ++i)
#pragma unroll
    for (int j = 0; j < 4; ++j) acc[i][j] = (f32x4){0.f, 0.f, 0.f, 0.f};

  for (int kt = 0; kt < K; kt += 64) {
#pragma unroll
    for (int it = 0; it < 4; ++it) {
      int r = rs + it * 32;
      int c8 = uP ^ (r & 7);
      gload_lds16(A  + ((size_t)(m0 + r) * K + kt + c8 * 8), Asm + r * 128 + uP * 16);
      gload_lds16(Bt + ((size_t)(n0 + r) * K + kt + c8 * 8), Bsm + r * 128 + uP * 16);
    }
    __syncthreads();
#pragma unroll
    for (int kk = 0; kk < 2; ++kk) {
      bf16x8 af[4], bfr[4];
      int uL = kk * 4 + gi;
#pragma unroll
      for (int i = 0; i < 4; ++i) {
        int ra = wr * 64 + i * 16 + c0;
        af[i] = *(const bf16x8*)(Asm + ra * 128 + ((uL ^ (ra & 7)) * 16));
        int rb = wc * 64 + i * 16 + c0;
        bfr[i] = *(const bf16x8*)(Bsm + rb * 128 + ((uL ^ (rb & 7)) * 16));
      }
#pragma unroll
      for (int i = 0; i < 4; ++i)
#pragma unroll
        for (int j = 0; j < 4; ++j)
          acc[i][j] = __builtin_amdgcn_mfma_f32_16x16x32_bf16(af[i], bfr[j], acc[i][j], 0, 0, 0);
    }
    __syncthreads();
  }

#pragma unroll
  for (int i = 0; i < 4; ++i) {
#pragma unroll
    for (int j = 0; j < 4; ++j) {
#pragma unroll
      for (int rI = 0; rI < 4; ++rI) {
        int m = m0 + wr * 64 + i * 16 + gi * 4 + rI;
        int n = n0 + wc * 64 + j * 16 + c0;
        float v = acc[i][j][rI] + bias[n];
        if (MODE == 1) {
          Cf[(size_t)m * N + n] = v;
        } else {
          int b = m >> 11, s = m & 2047;
          int which = n >> 10, w2 = n & 1023;
          int h = w2 >> 6, dk = w2 & 63;
          size_t hoff = (size_t)(b * NH + h);
          if (which == 0) {
            qo[(hoff * S_LEN + s) * DKH + dk] = f2bf(v * QK_SCALE_L2E);
          } else if (which == 1) {
            ko[(hoff * S_LEN + s) * DKH + dk] = f2bf(v);
          } else {
            vto[(hoff * DKH + dk) * S_LEN + s] = f2bf(v);
          }
        }
      }
    }
  }
}

// ---------------- split-KV flash attention work table (LPT order) -----------
struct WorkItem { unsigned char qt, t0, nt; };
__device__ __constant__ WorkItem g_items[48] = {
  {15,0,16},
  {16,0,16},{17,0,16},{18,0,16},{19,0,16},{20,0,16},{21,0,16},{22,0,16},{23,0,16},
  {24,0,16},{25,0,16},{26,0,16},{27,0,16},{28,0,16},{29,0,16},{30,0,16},{31,0,16},
  {31,16,16},
  {14,0,15},{30,16,15},
  {13,0,14},{29,16,14},
  {12,0,13},{28,16,13},
  {11,0,12},{27,16,12},
  {10,0,11},{26,16,11},
  { 9,0,10},{25,16,10},
  { 8,0, 9},{24,16, 9},
  { 7,0, 8},{23,16, 8},
  { 6,0, 7},{22,16, 7},
  { 5,0, 6},{21,16, 6},
  { 4,0, 5},{20,16, 5},
  { 3,0, 4},{19,16, 4},
  { 2,0, 3},{18,16, 3},
  { 1,0, 2},{17,16, 2},
  { 0,0, 1},{16,16, 1},
};

// ---------------- flash attention (partial), swapped-QK^T in-reg softmax ----
__global__ __launch_bounds__(256) void attn_part(
    const unsigned short* __restrict__ Q,   // [BH, S, 64] bf16, pre-scaled
    const unsigned short* __restrict__ Kb,  // [BH, S, 64] bf16
    const unsigned short* __restrict__ Vt,  // [BH, 64, S] bf16
    unsigned short* __restrict__ pO,        // [1536][64][64] bf16
    float* __restrict__ pm,                 // [1536][64]
    float* __restrict__ pl)                 // [1536][64]
{
  __shared__ __align__(16) char kbuf[64 * 128];
  __shared__ __align__(16) char vbuf[2][64 * 128];
  __shared__ __align__(16) unsigned short pbuf[4][16][88];  // 176B rows
  int t = threadIdx.x;
  int lane = t & 63, wid = t >> 6;
  int gi = lane >> 4, c0 = lane & 15;
  WorkItem wi = g_items[blockIdx.x];
  int bh = blockIdx.y;
  int qt = wi.qt, tile0 = wi.t0, nt = wi.nt;
  int pid = bh * 48 + (tile0 ? (32 + qt - 16) : qt);
  int q0 = qt << 6;
  const unsigned short* Qh = Q  + (size_t)bh * S_LEN * DKH;
  const unsigned short* Kh = Kb + (size_t)bh * S_LEN * DKH;
  const unsigned short* Vh = Vt + (size_t)bh * DKH * S_LEN;

  bf16x8 qf[2];
  {
    int qrow = q0 + wid * 16 + c0;
#pragma unroll
    for (int ks = 0; ks < 2; ++ks)
      qf[ks] = *(const bf16x8*)(Qh + (size_t)qrow * DKH + ks * 32 + gi * 8);
  }

  float mrow = -1e30f, lrow = 0.f;
  f32x4 o[4];
#pragma unroll
  for (int i = 0; i < 4; ++i) o[i] = (f32x4){0, 0, 0, 0};

  int rs = t >> 3, uP = t & 7;
  int q_abs = q0 + wid * 16 + c0;

  int c8 = uP ^ (rs & 7);
  const unsigned short* kp0 = Kh + ((size_t)(tile0 * 64 + rs) * DKH) + c8 * 8;
  const unsigned short* kp1 = kp0 + 32 * DKH;
  const unsigned short* vp0 = Vh + (size_t)rs * S_LEN + tile0 * 64 + c8 * 8;
  const unsigned short* vp1 = vp0 + (size_t)32 * S_LEN;
  char* klds0 = kbuf + rs * 128 + uP * 16;
  char* klds1 = klds0 + 32 * 128;
  int vlds_off0 = rs * 128 + uP * 16;

  gload_lds16(kp0, klds0);
  gload_lds16(kp1, klds1);
  gload_lds16(vp0, vbuf[0] + vlds_off0);
  gload_lds16(vp1, vbuf[0] + vlds_off0 + 32 * 128);
  kp0 += 64 * DKH; kp1 += 64 * DKH; vp0 += 64; vp1 += 64;

  for (int tt = 0; tt < nt; ++tt) {
    int tile = tile0 + tt;
    int kv0 = tile << 6;
    __syncthreads();   // staged K(t), V(t) landed

    // S^T = K * Q^T: sc[f][i] = S[q=c0][kv = kv0 + f*16 + gi*4 + i]
    f32x4 sc[4];
#pragma unroll
    for (int f = 0; f < 4; ++f) {
      f32x4 s = (f32x4){0, 0, 0, 0};
#pragma unroll
      for (int ks = 0; ks < 2; ++ks) {
        int rb = f * 16 + c0;
        int uL = ks * 4 + gi;
        bf16x8 kf = *(const bf16x8*)(kbuf + rb * 128 + ((uL ^ (rb & 7)) * 16));
        s = __builtin_amdgcn_mfma_f32_16x16x32_bf16(kf, qf[ks], s, 0, 0, 0);
      }
      sc[f] = s;
    }
    __syncthreads();   // all waves done reading kbuf

    if (tt + 1 < nt) {
      char* vb = vbuf[(tt + 1) & 1];
      gload_lds16(kp0, klds0);
      gload_lds16(kp1, klds1);
      gload_lds16(vp0, vb + vlds_off0);
      gload_lds16(vp1, vb + vlds_off0 + 32 * 128);
      kp0 += 64 * DKH; kp1 += 64 * DKH; vp0 += 64; vp1 += 64;
    }

    if (tile == qt) {
      int kvb = kv0 + gi * 4;
#pragma unroll
      for (int f = 0; f < 4; ++f)
#pragma unroll
        for (int i = 0; i < 4; ++i)
          if (kvb + f * 16 + i > q_abs) sc[f][i] = -1e30f;
    }

    float m01 = fmaxf(fmaxf(sc[0][0], sc[0][1]), fmaxf(sc[0][2], sc[0][3]));
    float m23 = fmaxf(fmaxf(sc[1][0], sc[1][1]), fmaxf(sc[1][2], sc[1][3]));
    float m45 = fmaxf(fmaxf(sc[2][0], sc[2][1]), fmaxf(sc[2][2], sc[2][3]));
    float m67 = fmaxf(fmaxf(sc[3][0], sc[3][1]), fmaxf(sc[3][2], sc[3][3]));
    float tmax = fmaxf(fmaxf(m01, m23), fmaxf(m45, m67));
    tmax = fmaxf(tmax, __shfl_xor(tmax, 16));
    tmax = fmaxf(tmax, __shfl_xor(tmax, 32));

    float alpha = 1.f;
    if (__any(tmax > mrow)) {
      float mnew = fmaxf(mrow, tmax);
      alpha = exp2a(mrow - mnew);
      mrow = mnew;
      float af0 = __shfl(alpha, gi * 4 + 0);
      float af1 = __shfl(alpha, gi * 4 + 1);
      float af2 = __shfl(alpha, gi * 4 + 2);
      float af3 = __shfl(alpha, gi * 4 + 3);
#pragma unroll
      for (int df = 0; df < 4; ++df) {
        o[df][0] *= af0; o[df][1] *= af1; o[df][2] *= af2; o[df][3] *= af3;
      }
    }

    float ps0 = 0, ps1 = 0, ps2 = 0, ps3 = 0;
#pragma unroll
    for (int f = 0; f < 4; ++f) {
      float p0 = exp2a(sc[f][0] - mrow);
      float p1 = exp2a(sc[f][1] - mrow);
      float p2 = exp2a(sc[f][2] - mrow);
      float p3 = exp2a(sc[f][3] - mrow);
      sc[f][0] = p0; sc[f][1] = p1; sc[f][2] = p2; sc[f][3] = p3;
      ps0 += p0; ps1 += p1; ps2 += p2; ps3 += p3;
    }
    float ps = (ps0 + ps1) + (ps2 + ps3);
    ps += __shfl_xor(ps, 16);
    ps += __shfl_xor(ps, 32);
    lrow = lrow * alpha + ps;

    {
      char* pbrow = (char*)&pbuf[wid][0][0] + c0 * 176;
#pragma unroll
      for (int f = 0; f < 4; ++f) {
        unsigned int u0 = cvtpk(sc[f][0], sc[f][1]);
        unsigned int u1 = cvtpk(sc[f][2], sc[f][3]);
        *(unsigned int*)(pbrow + (f * 16 + gi * 4) * 2)     = u0;
        *(unsigned int*)(pbrow + (f * 16 + gi * 4) * 2 + 4) = u1;
      }
    }
    asm volatile("s_waitcnt lgkmcnt(0)" ::: "memory");

    {
      const char* pb = (const char*)&pbuf[wid][0][0] + c0 * 176;
      const char* vcur = vbuf[tt & 1];
#pragma unroll
      for (int ks = 0; ks < 2; ++ks) {
        bf16x8 pa = *(const bf16x8*)(pb + ks * 64 + gi * 16);
#pragma unroll
        for (int df = 0; df < 4; ++df) {
          int rv = df * 16 + c0;
          int uL = ks * 4 + gi;
          bf16x8 vf = *(const bf16x8*)(vcur + rv * 128 + ((uL ^ (rv & 7)) * 16));
          o[df] = __builtin_amdgcn_mfma_f32_16x16x32_bf16(pa, vf, o[df], 0, 0, 0);
        }
      }
    }
  }

  unsigned short* po = pO + (size_t)pid * 4096;
#pragma unroll
  for (int i = 0; i < 4; ++i) {
    int r = wid * 16 + gi * 4 + i;
#pragma unroll
    for (int df = 0; df < 4; ++df)
      po[r * 64 + df * 16 + c0] = f2bf(o[df][i]);
  }
  if (lane < 16) {
    pm[pid * 64 + wid * 16 + c0] = mrow;
    pl[pid * 64 + wid * 16 + c0] = lrow;
  }
}

// ---------------- combine partials -> attn output [B*S, 1024] bf16 ----------
__global__ __launch_bounds__(256) void attn_combine(
    const unsigned short* __restrict__ pO,
    const float* __restrict__ pm,
    const float* __restrict__ pl,
    unsigned short* __restrict__ Out)
{
  int qt = blockIdx.x, bh = blockIdx.y;
  int t = threadIdx.x;
  int r = t >> 2, cseg = (t & 3) * 16;
  int pid0 = bh * 48 + qt;
  bool two = (qt >= 16);
  int pid1 = bh * 48 + 32 + qt - 16;

  float m0 = pm[pid0 * 64 + r];
  float l0 = pl[pid0 * 64 + r];
  float M = m0, w0 = 1.f, w1 = 0.f, l = l0;
  if (two) {
    float m1 = pm[pid1 * 64 + r];
    float l1 = pl[pid1 * 64 + r];
    M = fmaxf(m0, m1);
    w0 = exp2a(m0 - M);
    w1 = exp2a(m1 - M);
    l = w0 * l0 + w1 * l1;
  }
  float rl = 1.0f / l;

  const unsigned short* o0 = pO + (size_t)pid0 * 4096 + r * 64 + cseg;
  const unsigned short* o1 = pO + (size_t)pid1 * 4096 + r * 64 + cseg;
  int b = bh >> 4, h = bh & 15;
  size_t base = ((size_t)(b * S_LEN) + (qt * 64 + r)) * DM + h * DKH + cseg;

  bf16x8 a0 = *(const bf16x8*)o0;
  bf16x8 a1 = *(const bf16x8*)(o0 + 8);
  unsigned short res[16];
  if (two) {
    bf16x8 b0 = *(const bf16x8*)o1;
    bf16x8 b1 = *(const bf16x8*)(o1 + 8);
#pragma unroll
    for (int j = 0; j < 8; ++j) {
      res[j]     = f2bf((w0 * bf2f((unsigned short)a0[j]) + w1 * bf2f((unsigned short)b0[j])) * rl);
      res[j + 8] = f2bf((w0 * bf2f((unsigned short)a1[j]) + w1 * bf2f((unsigned short)b1[j])) * rl);
    }
  } else {
#pragma unroll
    for (int j = 0; j < 8; ++j) {
      res[j]     = f2bf(bf2f((unsigned short)a0[j]) * rl);
      res[j + 8] = f2bf(bf2f((unsigned short)a1[j]) * rl);
    }
  }
  *(u32x4*)(Out + base)     = *(u32x4*)res;
  *(u32x4*)(Out + base + 8) = *(u32x4*)(res + 8);
}

// ----------------------------------------------------------------------------
extern "C" void kernel_launch(void* const* d_in, const int* in_sizes, int n_in,
                              void* d_out, int out_size, void* d_ws, size_t ws_size,
                              hipStream_t stream) {
  const float* x       = (const float*)d_in[0];
  const float* w_atten = (const float*)d_in[1];
  const float* b_atten = (const float*)d_in[2];
  const float* w_proj  = (const float*)d_in[3];
  const float* b_proj  = (const float*)d_in[4];
  float* out = (float*)d_out;
  char* ws = (char*)d_ws;

  unsigned short* x_bf  = (unsigned short*)(ws);
  unsigned short* wa_bf = (unsigned short*)(ws + ((size_t)8  << 20));
  unsigned short* wp_bf = (unsigned short*)(ws + ((size_t)14 << 20));
  unsigned short* q_bf  = (unsigned short*)(ws + ((size_t)16 << 20));
  unsigned short* k_bf  = (unsigned short*)(ws + ((size_t)24 << 20));
  unsigned short* vt_bf = (unsigned short*)(ws + ((size_t)32 << 20));
  unsigned short* at_bf = (unsigned short*)(ws + ((size_t)40 << 20));
  // partial buffers overlay x_bf/wa_bf (dead after gemm0)
  unsigned short* pO = (unsigned short*)(ws);
  float* pm = (float*)(ws + 12582912);
  float* pl = (float*)(ws + 12976128);

  cvt_f32_to_bf16<<<2048, 256, 0, stream>>>(x, x_bf, 4194304);
  cvt_f32_to_bf16<<<1536, 256, 0, stream>>>(w_atten, wa_bf, 3145728);
  cvt_f32_to_bf16<<<512, 256, 0, stream>>>(w_proj, wp_bf, 1048576);

  gemm4p<0><<<dim3(12, 16), 512, 0, stream>>>(x_bf, wa_bf, b_atten, nullptr,
                                              q_bf, k_bf, vt_bf, 4096, 3072, 1024);
  attn_part<<<dim3(48, 32), 256, 0, stream>>>(q_bf, k_bf, vt_bf, pO, pm, pl);
  attn_combine<<<dim3(32, 32), 256, 0, stream>>>(pO, pm, pl, at_bf);
  gemm_bt<1><<<dim3(8, 32), 256, 0, stream>>>(at_bf, wp_bf, b_proj, out,
                                              nullptr, nullptr, nullptr, 4096, 1024, 1024);
}

// Round 8
// 142.503 us; speedup vs baseline: 1.1866x; 1.1093x over previous
//
#include <hip/hip_runtime.h>
#include <hip/hip_bf16.h>

#define S_LEN 2048
#define NH 16
#define DKH 64
#define DM 1024
// 1/sqrt(64) * log2(e): folded into Q at the QKV-GEMM epilogue
#define QK_SCALE_L2E 0.1803368801111244f

typedef __attribute__((ext_vector_type(8))) short bf16x8;
typedef __attribute__((ext_vector_type(4))) float f32x4;
typedef __attribute__((ext_vector_type(4))) unsigned int u32x4;

__device__ __forceinline__ unsigned short f2bf(float f) {
  unsigned int x = __builtin_bit_cast(unsigned int, f);
  x += 0x7fffu + ((x >> 16) & 1u);   // RNE
  return (unsigned short)(x >> 16);
}
__device__ __forceinline__ float bf2f(unsigned short u) {
  unsigned int x = ((unsigned int)u) << 16;
  return __builtin_bit_cast(float, x);
}
__device__ __forceinline__ float exp2a(float x) {
  float r; asm("v_exp_f32 %0, %1" : "=v"(r) : "v"(x)); return r;
}
__device__ __forceinline__ unsigned int cvtpk(float a, float b) {
  unsigned int r; asm("v_cvt_pk_bf16_f32 %0, %1, %2" : "=v"(r) : "v"(a), "v"(b)); return r;
}

__device__ __forceinline__ void gload_lds16(const void* g, void* l) {
  __builtin_amdgcn_global_load_lds(
      (const __attribute__((address_space(1))) unsigned int*)g,
      (__attribute__((address_space(3))) unsigned int*)l, 16, 0, 0);
}

// ---------------- fp32 -> bf16 conversion (memory-bound pre-pass) -----------
__global__ void cvt_f32_to_bf16(const float* __restrict__ in,
                                unsigned short* __restrict__ out, int n) {
  int i = (blockIdx.x * blockDim.x + threadIdx.x) * 8;
  if (i >= n) return;
  float4 a = *(const float4*)(in + i);
  float4 b = *(const float4*)(in + i + 4);
  union { unsigned short us[8]; u32x4 v; } r;
  r.us[0] = f2bf(a.x); r.us[1] = f2bf(a.y); r.us[2] = f2bf(a.z); r.us[3] = f2bf(a.w);
  r.us[4] = f2bf(b.x); r.us[5] = f2bf(b.y); r.us[6] = f2bf(b.z); r.us[7] = f2bf(b.w);
  *(u32x4*)(out + i) = r.v;
}

// ========= 128x128 bf16 GEMM, BK=32, 4-slot LDS, 3-tiles-ahead prefetch =====
// 256 threads (4 waves, 2M x 2N). Per tile: wait vmcnt(8) [tiles t+1,t+2 in
// flight, tile t resident -- loads issued 3 tiles earlier]; one barrier;
// 8 ds_read_b128 (conflict-free row-pair packed layout, no swizzle needed);
// issue tile t+3's 4 loads; 16 MFMA. Loop never drains vmcnt until the tail.
// LDS 64KB -> 2 blocks/CU resident for cross-block stagger.
template<int MODE>
__global__ __launch_bounds__(256, 2) void gemm_dp(
    const unsigned short* __restrict__ A,   // [M,K] bf16 row-major
    const unsigned short* __restrict__ Bt,  // [N,K] bf16 row-major
    const float* __restrict__ bias,         // [N]
    float* __restrict__ Cf,                 // MODE 1
    unsigned short* __restrict__ qo,        // MODE 0
    unsigned short* __restrict__ ko,
    unsigned short* __restrict__ vto,
    int M, int N, int K)
{
  __shared__ __align__(16) char LA[4][8192];   // tile slot: 128 rows x 32 bf16
  __shared__ __align__(16) char LB[4][8192];   // packed 2 rows per 128B line
  int t = threadIdx.x;
  int lane = t & 63, wid = t >> 6;
  int wr = wid >> 1, wc = wid & 1;
  int m0 = blockIdx.y << 7, n0 = blockIdx.x << 7;
  int gi = lane >> 4, c0 = lane & 15;
  int rs = t >> 3, uP = t & 7;               // rs in [0,32)

  f32x4 acc[4][4];
#pragma unroll
  for (int i = 0; i < 4; ++i)
#pragma unroll
    for (int j = 0; j < 4; ++j) acc[i][j] = (f32x4){0.f, 0.f, 0.f, 0.f};

  // staging map (linear LDS, rule-21 safe): LDS byte rs*128+uP*16 holds
  // row 2*rs+(uP>>2) (+64 in round 1), k-chunk (uP&3)*8.
  int srow = 2 * rs + (uP >> 2);
  int scol = (uP & 3) * 8;
  const unsigned short* ap0 = A  + (size_t)(m0 + srow) * K + scol;
  const unsigned short* ap1 = ap0 + (size_t)64 * K;
  const unsigned short* bp0 = Bt + (size_t)(n0 + srow) * K + scol;
  const unsigned short* bp1 = bp0 + (size_t)64 * K;
  int la0 = rs * 128 + uP * 16, la1 = la0 + 4096;

#define STG(s)                                                     \
  do {                                                             \
    gload_lds16(ap0, LA[s] + la0); gload_lds16(ap1, LA[s] + la1);  \
    gload_lds16(bp0, LB[s] + la0); gload_lds16(bp1, LB[s] + la1);  \
    ap0 += 32; ap1 += 32; bp0 += 32; bp1 += 32;                    \
  } while (0)

  const int NT = K >> 5;                     // 32 tiles at K=1024
  STG(0); STG(1); STG(2);                    // 3-deep prologue (12 loads)

  for (int kt = 0; kt < NT; ++kt) {
    int cs = kt & 3;
    if (kt < NT - 2)       asm volatile("s_waitcnt vmcnt(8)" ::: "memory");
    else if (kt == NT - 2) asm volatile("s_waitcnt vmcnt(4)" ::: "memory");
    else                   asm volatile("s_waitcnt vmcnt(0)" ::: "memory");
    __builtin_amdgcn_s_barrier();

    const char* cA = LA[cs];
    const char* cB = LB[cs];
    bf16x8 af[4], bfr[4];
#pragma unroll
    for (int m = 0; m < 4; ++m) {
      int ra = wr * 64 + m * 16 + c0;
      af[m] = *(const bf16x8*)(cA + (ra >> 1) * 128 + ((ra & 1) * 4 + gi) * 16);
    }
#pragma unroll
    for (int n = 0; n < 4; ++n) {
      int rb = wc * 64 + n * 16 + c0;
      bfr[n] = *(const bf16x8*)(cB + (rb >> 1) * 128 + ((rb & 1) * 4 + gi) * 16);
    }
    if (kt < NT - 3) STG((kt + 3) & 3);      // keep 3 tiles in flight

    __builtin_amdgcn_s_setprio(1);
#pragma unroll
    for (int m = 0; m < 4; ++m)
#pragma unroll
      for (int n = 0; n < 4; ++n)
        acc[m][n] = __builtin_amdgcn_mfma_f32_16x16x32_bf16(af[m], bfr[n], acc[m][n], 0, 0, 0);
    __builtin_amdgcn_s_setprio(0);
  }
#undef STG

#pragma unroll
  for (int i = 0; i < 4; ++i) {
#pragma unroll
    for (int j = 0; j < 4; ++j) {
#pragma unroll
      for (int rI = 0; rI < 4; ++rI) {
        int m = m0 + wr * 64 + i * 16 + gi * 4 + rI;
        int n = n0 + wc * 64 + j * 16 + c0;
        float v = acc[i][j][rI] + bias[n];
        if (MODE == 1) {
          Cf[(size_t)m * N + n] = v;
        } else {
          int b = m >> 11, s = m & 2047;
          int which = n >> 10, w2 = n & 1023;
          int h = w2 >> 6, dk = w2 & 63;
          size_t hoff = (size_t)(b * NH + h);
          if (which == 0) {
            qo[(hoff * S_LEN + s) * DKH + dk] = f2bf(v * QK_SCALE_L2E);
          } else if (which == 1) {
            ko[(hoff * S_LEN + s) * DKH + dk] = f2bf(v);
          } else {
            vto[(hoff * DKH + dk) * S_LEN + s] = f2bf(v);  // V transposed
          }
        }
      }
    }
  }
}

// ---------------- split-KV flash attention work table (LPT order) -----------
struct WorkItem { unsigned char qt, t0, nt; };
__device__ __constant__ WorkItem g_items[48] = {
  {15,0,16},
  {16,0,16},{17,0,16},{18,0,16},{19,0,16},{20,0,16},{21,0,16},{22,0,16},{23,0,16},
  {24,0,16},{25,0,16},{26,0,16},{27,0,16},{28,0,16},{29,0,16},{30,0,16},{31,0,16},
  {31,16,16},
  {14,0,15},{30,16,15},
  {13,0,14},{29,16,14},
  {12,0,13},{28,16,13},
  {11,0,12},{27,16,12},
  {10,0,11},{26,16,11},
  { 9,0,10},{25,16,10},
  { 8,0, 9},{24,16, 9},
  { 7,0, 8},{23,16, 8},
  { 6,0, 7},{22,16, 7},
  { 5,0, 6},{21,16, 6},
  { 4,0, 5},{20,16, 5},
  { 3,0, 4},{19,16, 4},
  { 2,0, 3},{18,16, 3},
  { 1,0, 2},{17,16, 2},
  { 0,0, 1},{16,16, 1},
};

// ---------------- flash attention (partial), swapped-QK^T in-reg softmax ----
__global__ __launch_bounds__(256) void attn_part(
    const unsigned short* __restrict__ Q,   // [BH, S, 64] bf16, pre-scaled
    const unsigned short* __restrict__ Kb,  // [BH, S, 64] bf16
    const unsigned short* __restrict__ Vt,  // [BH, 64, S] bf16
    unsigned short* __restrict__ pO,        // [1536][64][64] bf16
    float* __restrict__ pm,                 // [1536][64]
    float* __restrict__ pl)                 // [1536][64]
{
  __shared__ __align__(16) char kbuf[64 * 128];
  __shared__ __align__(16) char vbuf[2][64 * 128];
  __shared__ __align__(16) unsigned short pbuf[4][16][88];  // 176B rows
  int t = threadIdx.x;
  int lane = t & 63, wid = t >> 6;
  int gi = lane >> 4, c0 = lane & 15;
  WorkItem wi = g_items[blockIdx.x];
  int bh = blockIdx.y;
  int qt = wi.qt, tile0 = wi.t0, nt = wi.nt;
  int pid = bh * 48 + (tile0 ? (32 + qt - 16) : qt);
  int q0 = qt << 6;
  const unsigned short* Qh = Q  + (size_t)bh * S_LEN * DKH;
  const unsigned short* Kh = Kb + (size_t)bh * S_LEN * DKH;
  const unsigned short* Vh = Vt + (size_t)bh * DKH * S_LEN;

  bf16x8 qf[2];
  {
    int qrow = q0 + wid * 16 + c0;
#pragma unroll
    for (int ks = 0; ks < 2; ++ks)
      qf[ks] = *(const bf16x8*)(Qh + (size_t)qrow * DKH + ks * 32 + gi * 8);
  }

  float mrow = -1e30f, lrow = 0.f;
  f32x4 o[4];
#pragma unroll
  for (int i = 0; i < 4; ++i) o[i] = (f32x4){0, 0, 0, 0};

  int rs = t >> 3, uP = t & 7;
  int q_abs = q0 + wid * 16 + c0;

  int c8 = uP ^ (rs & 7);
  const unsigned short* kp0 = Kh + ((size_t)(tile0 * 64 + rs) * DKH) + c8 * 8;
  const unsigned short* kp1 = kp0 + 32 * DKH;
  const unsigned short* vp0 = Vh + (size_t)rs * S_LEN + tile0 * 64 + c8 * 8;
  const unsigned short* vp1 = vp0 + (size_t)32 * S_LEN;
  char* klds0 = kbuf + rs * 128 + uP * 16;
  char* klds1 = klds0 + 32 * 128;
  int vlds_off0 = rs * 128 + uP * 16;

  gload_lds16(kp0, klds0);
  gload_lds16(kp1, klds1);
  gload_lds16(vp0, vbuf[0] + vlds_off0);
  gload_lds16(vp1, vbuf[0] + vlds_off0 + 32 * 128);
  kp0 += 64 * DKH; kp1 += 64 * DKH; vp0 += 64; vp1 += 64;

  for (int tt = 0; tt < nt; ++tt) {
    int tile = tile0 + tt;
    int kv0 = tile << 6;
    __syncthreads();   // staged K(t), V(t) landed

    // S^T = K * Q^T: sc[f][i] = S[q=c0][kv = kv0 + f*16 + gi*4 + i]
    f32x4 sc[4];
#pragma unroll
    for (int f = 0; f < 4; ++f) {
      f32x4 s = (f32x4){0, 0, 0, 0};
#pragma unroll
      for (int ks = 0; ks < 2; ++ks) {
        int rb = f * 16 + c0;
        int uL = ks * 4 + gi;
        bf16x8 kf = *(const bf16x8*)(kbuf + rb * 128 + ((uL ^ (rb & 7)) * 16));
        s = __builtin_amdgcn_mfma_f32_16x16x32_bf16(kf, qf[ks], s, 0, 0, 0);
      }
      sc[f] = s;
    }
    __syncthreads();   // all waves done reading kbuf

    if (tt + 1 < nt) {
      char* vb = vbuf[(tt + 1) & 1];
      gload_lds16(kp0, klds0);
      gload_lds16(kp1, klds1);
      gload_lds16(vp0, vb + vlds_off0);
      gload_lds16(vp1, vb + vlds_off0 + 32 * 128);
      kp0 += 64 * DKH; kp1 += 64 * DKH; vp0 += 64; vp1 += 64;
    }

    if (tile == qt) {
      int kvb = kv0 + gi * 4;
#pragma unroll
      for (int f = 0; f < 4; ++f)
#pragma unroll
        for (int i = 0; i < 4; ++i)
          if (kvb + f * 16 + i > q_abs) sc[f][i] = -1e30f;
    }

    float m01 = fmaxf(fmaxf(sc[0][0], sc[0][1]), fmaxf(sc[0][2], sc[0][3]));
    float m23 = fmaxf(fmaxf(sc[1][0], sc[1][1]), fmaxf(sc[1][2], sc[1][3]));
    float m45 = fmaxf(fmaxf(sc[2][0], sc[2][1]), fmaxf(sc[2][2], sc[2][3]));
    float m67 = fmaxf(fmaxf(sc[3][0], sc[3][1]), fmaxf(sc[3][2], sc[3][3]));
    float tmax = fmaxf(fmaxf(m01, m23), fmaxf(m45, m67));
    tmax = fmaxf(tmax, __shfl_xor(tmax, 16));
    tmax = fmaxf(tmax, __shfl_xor(tmax, 32));

    float alpha = 1.f;
    if (__any(tmax > mrow)) {
      float mnew = fmaxf(mrow, tmax);
      alpha = exp2a(mrow - mnew);
      mrow = mnew;
      float af0 = __shfl(alpha, gi * 4 + 0);
      float af1 = __shfl(alpha, gi * 4 + 1);
      float af2 = __shfl(alpha, gi * 4 + 2);
      float af3 = __shfl(alpha, gi * 4 + 3);
#pragma unroll
      for (int df = 0; df < 4; ++df) {
        o[df][0] *= af0; o[df][1] *= af1; o[df][2] *= af2; o[df][3] *= af3;
      }
    }

    float ps0 = 0, ps1 = 0, ps2 = 0, ps3 = 0;
#pragma unroll
    for (int f = 0; f < 4; ++f) {
      float p0 = exp2a(sc[f][0] - mrow);
      float p1 = exp2a(sc[f][1] - mrow);
      float p2 = exp2a(sc[f][2] - mrow);
      float p3 = exp2a(sc[f][3] - mrow);
      sc[f][0] = p0; sc[f][1] = p1; sc[f][2] = p2; sc[f][3] = p3;
      ps0 += p0; ps1 += p1; ps2 += p2; ps3 += p3;
    }
    float ps = (ps0 + ps1) + (ps2 + ps3);
    ps += __shfl_xor(ps, 16);
    ps += __shfl_xor(ps, 32);
    lrow = lrow * alpha + ps;

    {
      char* pbrow = (char*)&pbuf[wid][0][0] + c0 * 176;
#pragma unroll
      for (int f = 0; f < 4; ++f) {
        unsigned int u0 = cvtpk(sc[f][0], sc[f][1]);
        unsigned int u1 = cvtpk(sc[f][2], sc[f][3]);
        *(unsigned int*)(pbrow + (f * 16 + gi * 4) * 2)     = u0;
        *(unsigned int*)(pbrow + (f * 16 + gi * 4) * 2 + 4) = u1;
      }
    }
    asm volatile("s_waitcnt lgkmcnt(0)" ::: "memory");

    {
      const char* pb = (const char*)&pbuf[wid][0][0] + c0 * 176;
      const char* vcur = vbuf[tt & 1];
#pragma unroll
      for (int ks = 0; ks < 2; ++ks) {
        bf16x8 pa = *(const bf16x8*)(pb + ks * 64 + gi * 16);
#pragma unroll
        for (int df = 0; df < 4; ++df) {
          int rv = df * 16 + c0;
          int uL = ks * 4 + gi;
          bf16x8 vf = *(const bf16x8*)(vcur + rv * 128 + ((uL ^ (rv & 7)) * 16));
          o[df] = __builtin_amdgcn_mfma_f32_16x16x32_bf16(pa, vf, o[df], 0, 0, 0);
        }
      }
    }
  }

  unsigned short* po = pO + (size_t)pid * 4096;
#pragma unroll
  for (int i = 0; i < 4; ++i) {
    int r = wid * 16 + gi * 4 + i;
#pragma unroll
    for (int df = 0; df < 4; ++df)
      po[r * 64 + df * 16 + c0] = f2bf(o[df][i]);
  }
  if (lane < 16) {
    pm[pid * 64 + wid * 16 + c0] = mrow;
    pl[pid * 64 + wid * 16 + c0] = lrow;
  }
}

// ---------------- combine partials -> attn output [B*S, 1024] bf16 ----------
__global__ __launch_bounds__(256) void attn_combine(
    const unsigned short* __restrict__ pO,
    const float* __restrict__ pm,
    const float* __restrict__ pl,
    unsigned short* __restrict__ Out)
{
  int qt = blockIdx.x, bh = blockIdx.y;
  int t = threadIdx.x;
  int r = t >> 2, cseg = (t & 3) * 16;
  int pid0 = bh * 48 + qt;
  bool two = (qt >= 16);
  int pid1 = bh * 48 + 32 + qt - 16;

  float m0 = pm[pid0 * 64 + r];
  float l0 = pl[pid0 * 64 + r];
  float M = m0, w0 = 1.f, w1 = 0.f, l = l0;
  if (two) {
    float m1 = pm[pid1 * 64 + r];
    float l1 = pl[pid1 * 64 + r];
    M = fmaxf(m0, m1);
    w0 = exp2a(m0 - M);
    w1 = exp2a(m1 - M);
    l = w0 * l0 + w1 * l1;
  }
  float rl = 1.0f / l;

  const unsigned short* o0 = pO + (size_t)pid0 * 4096 + r * 64 + cseg;
  const unsigned short* o1 = pO + (size_t)pid1 * 4096 + r * 64 + cseg;
  int b = bh >> 4, h = bh & 15;
  size_t base = ((size_t)(b * S_LEN) + (qt * 64 + r)) * DM + h * DKH + cseg;

  bf16x8 a0 = *(const bf16x8*)o0;
  bf16x8 a1 = *(const bf16x8*)(o0 + 8);
  unsigned short res[16];
  if (two) {
    bf16x8 b0 = *(const bf16x8*)o1;
    bf16x8 b1 = *(const bf16x8*)(o1 + 8);
#pragma unroll
    for (int j = 0; j < 8; ++j) {
      res[j]     = f2bf((w0 * bf2f((unsigned short)a0[j]) + w1 * bf2f((unsigned short)b0[j])) * rl);
      res[j + 8] = f2bf((w0 * bf2f((unsigned short)a1[j]) + w1 * bf2f((unsigned short)b1[j])) * rl);
    }
  } else {
#pragma unroll
    for (int j = 0; j < 8; ++j) {
      res[j]     = f2bf(bf2f((unsigned short)a0[j]) * rl);
      res[j + 8] = f2bf(bf2f((unsigned short)a1[j]) * rl);
    }
  }
  *(u32x4*)(Out + base)     = *(u32x4*)res;
  *(u32x4*)(Out + base + 8) = *(u32x4*)(res + 8);
}

// ----------------------------------------------------------------------------
extern "C" void kernel_launch(void* const* d_in, const int* in_sizes, int n_in,
                              void* d_out, int out_size, void* d_ws, size_t ws_size,
                              hipStream_t stream) {
  const float* x       = (const float*)d_in[0];
  const float* w_atten = (const float*)d_in[1];
  const float* b_atten = (const float*)d_in[2];
  const float* w_proj  = (const float*)d_in[3];
  const float* b_proj  = (const float*)d_in[4];
  float* out = (float*)d_out;
  char* ws = (char*)d_ws;

  unsigned short* x_bf  = (unsigned short*)(ws);
  unsigned short* wa_bf = (unsigned short*)(ws + ((size_t)8  << 20));
  unsigned short* wp_bf = (unsigned short*)(ws + ((size_t)14 << 20));
  unsigned short* q_bf  = (unsigned short*)(ws + ((size_t)16 << 20));
  unsigned short* k_bf  = (unsigned short*)(ws + ((size_t)24 << 20));
  unsigned short* vt_bf = (unsigned short*)(ws + ((size_t)32 << 20));
  unsigned short* at_bf = (unsigned short*)(ws + ((size_t)40 << 20));
  // partial buffers overlay x_bf/wa_bf (dead after gemm0)
  unsigned short* pO = (unsigned short*)(ws);
  float* pm = (float*)(ws + 12582912);
  float* pl = (float*)(ws + 12976128);

  cvt_f32_to_bf16<<<2048, 256, 0, stream>>>(x, x_bf, 4194304);
  cvt_f32_to_bf16<<<1536, 256, 0, stream>>>(w_atten, wa_bf, 3145728);
  cvt_f32_to_bf16<<<512, 256, 0, stream>>>(w_proj, wp_bf, 1048576);

  gemm_dp<0><<<dim3(24, 32), 256, 0, stream>>>(x_bf, wa_bf, b_atten, nullptr,
                                               q_bf, k_bf, vt_bf, 4096, 3072, 1024);
  attn_part<<<dim3(48, 32), 256, 0, stream>>>(q_bf, k_bf, vt_bf, pO, pm, pl);
  attn_combine<<<dim3(32, 32), 256, 0, stream>>>(pO, pm, pl, at_bf);
  gemm_dp<1><<<dim3(8, 32), 256, 0, stream>>>(at_bf, wp_bf, b_proj, out,
                                              nullptr, nullptr, nullptr, 4096, 1024, 1024);
}

// Round 9
// 121.316 us; speedup vs baseline: 1.3938x; 1.1746x over previous
//
#include <hip/hip_runtime.h>
#include <hip/hip_bf16.h>

#define S_LEN 2048
#define NH 16
#define DKH 64
#define DM 1024
// 1/sqrt(64) * log2(e): folded into Q at the QKV-GEMM epilogue
#define QK_SCALE_L2E 0.1803368801111244f

typedef __attribute__((ext_vector_type(8))) short bf16x8;
typedef __attribute__((ext_vector_type(4))) float f32x4;
typedef __attribute__((ext_vector_type(4))) unsigned int u32x4;

__device__ __forceinline__ unsigned short f2bf(float f) {
  unsigned int x = __builtin_bit_cast(unsigned int, f);
  x += 0x7fffu + ((x >> 16) & 1u);   // RNE
  return (unsigned short)(x >> 16);
}
__device__ __forceinline__ float bf2f(unsigned short u) {
  unsigned int x = ((unsigned int)u) << 16;
  return __builtin_bit_cast(float, x);
}
__device__ __forceinline__ float exp2a(float x) {
  float r; asm("v_exp_f32 %0, %1" : "=v"(r) : "v"(x)); return r;
}
__device__ __forceinline__ unsigned int cvtpk(float a, float b) {
  unsigned int r; asm("v_cvt_pk_bf16_f32 %0, %1, %2" : "=v"(r) : "v"(a), "v"(b)); return r;
}

__device__ __forceinline__ void gload_lds16(const void* g, void* l) {
  __builtin_amdgcn_global_load_lds(
      (const __attribute__((address_space(1))) unsigned int*)g,
      (__attribute__((address_space(3))) unsigned int*)l, 16, 0, 0);
}

// ---------------- fp32 -> bf16 conversion (memory-bound pre-pass) -----------
__global__ void cvt_f32_to_bf16(const float* __restrict__ in,
                                unsigned short* __restrict__ out, int n) {
  int i = (blockIdx.x * blockDim.x + threadIdx.x) * 8;
  if (i >= n) return;
  float4 a = *(const float4*)(in + i);
  float4 b = *(const float4*)(in + i + 4);
  union { unsigned short us[8]; u32x4 v; } r;
  r.us[0] = f2bf(a.x); r.us[1] = f2bf(a.y); r.us[2] = f2bf(a.z); r.us[3] = f2bf(a.w);
  r.us[4] = f2bf(b.x); r.us[5] = f2bf(b.y); r.us[6] = f2bf(b.z); r.us[7] = f2bf(b.w);
  *(u32x4*)(out + i) = r.v;
}

// ==== 128x128 bf16 GEMM, BK=32, 3-slot LDS, depth-2 prefetch, XCD-chunked ===
// The R8 structure with three fixes:
//  (1) XCD 2D-chunk swizzle: each XCD owns a contiguous (m x n) sub-grid so
//      its resident blocks' A/B panels fit the 4MB per-XCD L2 (kills the
//      L3-bandwidth bottleneck that pinned QKV at ~60us across 5 structures).
//  (2) slot XOR s = (h*4+k)^(p&7): conflict-free ds_read_b128 (R8 had 4-way).
//  (3) 3 slots (48KB LDS) -> 3 blocks/CU for cross-block stagger.
template<int MODE>
__global__ __launch_bounds__(256, 3) void gemm_x(
    const unsigned short* __restrict__ A,   // [M,K] bf16 row-major
    const unsigned short* __restrict__ Bt,  // [N,K] bf16 row-major
    const float* __restrict__ bias,         // [N]
    float* __restrict__ Cf,                 // MODE 1
    unsigned short* __restrict__ qo,        // MODE 0
    unsigned short* __restrict__ ko,
    unsigned short* __restrict__ vto,
    int M, int N, int K)
{
  __shared__ __align__(16) char LA[3][8192];   // slot: 128 rows x 32 bf16
  __shared__ __align__(16) char LB[3][8192];   // 2 rows packed per 128B line
  int t = threadIdx.x;
  int lane = t & 63, wid = t >> 6;
  int wr = wid >> 1, wc = wid & 1;

  // XCD-aware 2D chunk decode (bijective). MODE 0: grid (24,32) -> 8 XCD
  // chunks of 8m x 12n. MODE 1: grid (8,32) -> chunks of 4m x 8n.
  int bid = blockIdx.x + gridDim.x * blockIdx.y;
  int xcd = bid & 7, local = bid >> 3;
  int bx, by;
  if (MODE == 0) {
    int xm = xcd >> 1, xn = xcd & 1;        // 4 x 2 XCD layout
    by = xm * 8 + (local & 7);              // local in [0,96)
    bx = xn * 12 + (local >> 3);
  } else {
    by = xcd * 4 + (local >> 3);            // local in [0,32)
    bx = local & 7;
  }
  int m0 = by << 7, n0 = bx << 7;
  int gi = lane >> 4, c0 = lane & 15;
  int rs = t >> 3, uP = t & 7;               // rs in [0,32)

  f32x4 acc[4][4];
#pragma unroll
  for (int i = 0; i < 4; ++i)
#pragma unroll
    for (int j = 0; j < 4; ++j) acc[i][j] = (f32x4){0.f, 0.f, 0.f, 0.f};

  // staging (rule 21: linear LDS dest, pre-swizzled global src).
  // LDS line p, slot s holds row 2p + (u>>2), chunk u&3 where u = s^(p&7).
  int u = uP ^ (rs & 7);
  int srow = 2 * rs + (u >> 2);
  int scol = (u & 3) * 8;
  const unsigned short* ap0 = A  + (size_t)(m0 + srow) * K + scol;
  const unsigned short* ap1 = ap0 + (size_t)64 * K;   // line rs+32: same p&7
  const unsigned short* bp0 = Bt + (size_t)(n0 + srow) * K + scol;
  const unsigned short* bp1 = bp0 + (size_t)64 * K;
  int la0 = rs * 128 + uP * 16, la1 = la0 + 4096;

#define STG(s)                                                     \
  do {                                                             \
    gload_lds16(ap0, LA[s] + la0); gload_lds16(ap1, LA[s] + la1);  \
    gload_lds16(bp0, LB[s] + la0); gload_lds16(bp1, LB[s] + la1);  \
    ap0 += 32; ap1 += 32; bp0 += 32; bp1 += 32;                    \
  } while (0)

  const int NT = K >> 5;                     // 32 tiles at K=1024
  STG(0); STG(1);                            // depth-2 prologue (8 loads)

  int cs = 0, ss = 2;
  for (int kt = 0; kt < NT; ++kt) {
    if (kt < NT - 1) asm volatile("s_waitcnt vmcnt(4)" ::: "memory");
    else             asm volatile("s_waitcnt vmcnt(0)" ::: "memory");
    __builtin_amdgcn_s_barrier();

    const char* cA = LA[cs];
    const char* cB = LB[cs];
    bf16x8 af[4], bfr[4];
#pragma unroll
    for (int m = 0; m < 4; ++m) {
      int ra = wr * 64 + m * 16 + c0;
      int p = ra >> 1;
      af[m] = *(const bf16x8*)(cA + p * 128 + ((((ra & 1) * 4 + gi) ^ (p & 7)) * 16));
    }
#pragma unroll
    for (int n = 0; n < 4; ++n) {
      int rb = wc * 64 + n * 16 + c0;
      int p = rb >> 1;
      bfr[n] = *(const bf16x8*)(cB + p * 128 + ((((rb & 1) * 4 + gi) ^ (p & 7)) * 16));
    }
    if (kt < NT - 2) STG(ss);                // keep 2 tiles in flight

    __builtin_amdgcn_s_setprio(1);
#pragma unroll
    for (int m = 0; m < 4; ++m)
#pragma unroll
      for (int n = 0; n < 4; ++n)
        acc[m][n] = __builtin_amdgcn_mfma_f32_16x16x32_bf16(af[m], bfr[n], acc[m][n], 0, 0, 0);
    __builtin_amdgcn_s_setprio(0);

    cs = (cs == 2) ? 0 : cs + 1;
    ss = (ss == 2) ? 0 : ss + 1;
  }
#undef STG

#pragma unroll
  for (int i = 0; i < 4; ++i) {
#pragma unroll
    for (int j = 0; j < 4; ++j) {
#pragma unroll
      for (int rI = 0; rI < 4; ++rI) {
        int m = m0 + wr * 64 + i * 16 + gi * 4 + rI;
        int n = n0 + wc * 64 + j * 16 + c0;
        float v = acc[i][j][rI] + bias[n];
        if (MODE == 1) {
          Cf[(size_t)m * N + n] = v;
        } else {
          int b = m >> 11, s = m & 2047;
          int which = n >> 10, w2 = n & 1023;
          int h = w2 >> 6, dk = w2 & 63;
          size_t hoff = (size_t)(b * NH + h);
          if (which == 0) {
            qo[(hoff * S_LEN + s) * DKH + dk] = f2bf(v * QK_SCALE_L2E);
          } else if (which == 1) {
            ko[(hoff * S_LEN + s) * DKH + dk] = f2bf(v);
          } else {
            vto[(hoff * DKH + dk) * S_LEN + s] = f2bf(v);  // V transposed
          }
        }
      }
    }
  }
}

// ---------------- split-KV flash attention work table (LPT order) -----------
struct WorkItem { unsigned char qt, t0, nt; };
__device__ __constant__ WorkItem g_items[48] = {
  {15,0,16},
  {16,0,16},{17,0,16},{18,0,16},{19,0,16},{20,0,16},{21,0,16},{22,0,16},{23,0,16},
  {24,0,16},{25,0,16},{26,0,16},{27,0,16},{28,0,16},{29,0,16},{30,0,16},{31,0,16},
  {31,16,16},
  {14,0,15},{30,16,15},
  {13,0,14},{29,16,14},
  {12,0,13},{28,16,13},
  {11,0,12},{27,16,12},
  {10,0,11},{26,16,11},
  { 9,0,10},{25,16,10},
  { 8,0, 9},{24,16, 9},
  { 7,0, 8},{23,16, 8},
  { 6,0, 7},{22,16, 7},
  { 5,0, 6},{21,16, 6},
  { 4,0, 5},{20,16, 5},
  { 3,0, 4},{19,16, 4},
  { 2,0, 3},{18,16, 3},
  { 1,0, 2},{17,16, 2},
  { 0,0, 1},{16,16, 1},
};

// ---------------- flash attention (partial), swapped-QK^T in-reg softmax ----
// XCD swizzle: each XCD owns 4 heads -> K/V working set 2MB, L2-resident.
// Within an XCD, ascending local preserves LPT (long items first).
__global__ __launch_bounds__(256) void attn_part(
    const unsigned short* __restrict__ Q,   // [BH, S, 64] bf16, pre-scaled
    const unsigned short* __restrict__ Kb,  // [BH, S, 64] bf16
    const unsigned short* __restrict__ Vt,  // [BH, 64, S] bf16
    unsigned short* __restrict__ pO,        // [1536][64][64] bf16
    float* __restrict__ pm,                 // [1536][64]
    float* __restrict__ pl)                 // [1536][64]
{
  __shared__ __align__(16) char kbuf[64 * 128];
  __shared__ __align__(16) char vbuf[2][64 * 128];
  __shared__ __align__(16) unsigned short pbuf[4][16][88];  // 176B rows
  int t = threadIdx.x;
  int lane = t & 63, wid = t >> 6;
  int gi = lane >> 4, c0 = lane & 15;
  // grid (48,32): bid = item + 48*bh; remap so each XCD owns 4 heads.
  int bid = blockIdx.x + 48 * blockIdx.y;
  int xcd = bid & 7, local = bid >> 3;      // local in [0,192)
  int item = local >> 2;
  int bh = xcd * 4 + (local & 3);
  WorkItem wi = g_items[item];
  int qt = wi.qt, tile0 = wi.t0, nt = wi.nt;
  int pid = bh * 48 + (tile0 ? (32 + qt - 16) : qt);
  int q0 = qt << 6;
  const unsigned short* Qh = Q  + (size_t)bh * S_LEN * DKH;
  const unsigned short* Kh = Kb + (size_t)bh * S_LEN * DKH;
  const unsigned short* Vh = Vt + (size_t)bh * DKH * S_LEN;

  bf16x8 qf[2];
  {
    int qrow = q0 + wid * 16 + c0;
#pragma unroll
    for (int ks = 0; ks < 2; ++ks)
      qf[ks] = *(const bf16x8*)(Qh + (size_t)qrow * DKH + ks * 32 + gi * 8);
  }

  float mrow = -1e30f, lrow = 0.f;
  f32x4 o[4];
#pragma unroll
  for (int i = 0; i < 4; ++i) o[i] = (f32x4){0, 0, 0, 0};

  int rs = t >> 3, uP = t & 7;
  int q_abs = q0 + wid * 16 + c0;

  int c8 = uP ^ (rs & 7);
  const unsigned short* kp0 = Kh + ((size_t)(tile0 * 64 + rs) * DKH) + c8 * 8;
  const unsigned short* kp1 = kp0 + 32 * DKH;
  const unsigned short* vp0 = Vh + (size_t)rs * S_LEN + tile0 * 64 + c8 * 8;
  const unsigned short* vp1 = vp0 + (size_t)32 * S_LEN;
  char* klds0 = kbuf + rs * 128 + uP * 16;
  char* klds1 = klds0 + 32 * 128;
  int vlds_off0 = rs * 128 + uP * 16;

  gload_lds16(kp0, klds0);
  gload_lds16(kp1, klds1);
  gload_lds16(vp0, vbuf[0] + vlds_off0);
  gload_lds16(vp1, vbuf[0] + vlds_off0 + 32 * 128);
  kp0 += 64 * DKH; kp1 += 64 * DKH; vp0 += 64; vp1 += 64;

  for (int tt = 0; tt < nt; ++tt) {
    int tile = tile0 + tt;
    int kv0 = tile << 6;
    __syncthreads();   // staged K(t), V(t) landed

    // S^T = K * Q^T: sc[f][i] = S[q=c0][kv = kv0 + f*16 + gi*4 + i]
    f32x4 sc[4];
#pragma unroll
    for (int f = 0; f < 4; ++f) {
      f32x4 s = (f32x4){0, 0, 0, 0};
#pragma unroll
      for (int ks = 0; ks < 2; ++ks) {
        int rb = f * 16 + c0;
        int uL = ks * 4 + gi;
        bf16x8 kf = *(const bf16x8*)(kbuf + rb * 128 + ((uL ^ (rb & 7)) * 16));
        s = __builtin_amdgcn_mfma_f32_16x16x32_bf16(kf, qf[ks], s, 0, 0, 0);
      }
      sc[f] = s;
    }
    __syncthreads();   // all waves done reading kbuf

    if (tt + 1 < nt) {
      char* vb = vbuf[(tt + 1) & 1];
      gload_lds16(kp0, klds0);
      gload_lds16(kp1, klds1);
      gload_lds16(vp0, vb + vlds_off0);
      gload_lds16(vp1, vb + vlds_off0 + 32 * 128);
      kp0 += 64 * DKH; kp1 += 64 * DKH; vp0 += 64; vp1 += 64;
    }

    if (tile == qt) {
      int kvb = kv0 + gi * 4;
#pragma unroll
      for (int f = 0; f < 4; ++f)
#pragma unroll
        for (int i = 0; i < 4; ++i)
          if (kvb + f * 16 + i > q_abs) sc[f][i] = -1e30f;
    }

    float m01 = fmaxf(fmaxf(sc[0][0], sc[0][1]), fmaxf(sc[0][2], sc[0][3]));
    float m23 = fmaxf(fmaxf(sc[1][0], sc[1][1]), fmaxf(sc[1][2], sc[1][3]));
    float m45 = fmaxf(fmaxf(sc[2][0], sc[2][1]), fmaxf(sc[2][2], sc[2][3]));
    float m67 = fmaxf(fmaxf(sc[3][0], sc[3][1]), fmaxf(sc[3][2], sc[3][3]));
    float tmax = fmaxf(fmaxf(m01, m23), fmaxf(m45, m67));
    tmax = fmaxf(tmax, __shfl_xor(tmax, 16));
    tmax = fmaxf(tmax, __shfl_xor(tmax, 32));

    float alpha = 1.f;
    if (__any(tmax > mrow)) {
      float mnew = fmaxf(mrow, tmax);
      alpha = exp2a(mrow - mnew);
      mrow = mnew;
      float af0 = __shfl(alpha, gi * 4 + 0);
      float af1 = __shfl(alpha, gi * 4 + 1);
      float af2 = __shfl(alpha, gi * 4 + 2);
      float af3 = __shfl(alpha, gi * 4 + 3);
#pragma unroll
      for (int df = 0; df < 4; ++df) {
        o[df][0] *= af0; o[df][1] *= af1; o[df][2] *= af2; o[df][3] *= af3;
      }
    }

    float ps0 = 0, ps1 = 0, ps2 = 0, ps3 = 0;
#pragma unroll
    for (int f = 0; f < 4; ++f) {
      float p0 = exp2a(sc[f][0] - mrow);
      float p1 = exp2a(sc[f][1] - mrow);
      float p2 = exp2a(sc[f][2] - mrow);
      float p3 = exp2a(sc[f][3] - mrow);
      sc[f][0] = p0; sc[f][1] = p1; sc[f][2] = p2; sc[f][3] = p3;
      ps0 += p0; ps1 += p1; ps2 += p2; ps3 += p3;
    }
    float ps = (ps0 + ps1) + (ps2 + ps3);
    ps += __shfl_xor(ps, 16);
    ps += __shfl_xor(ps, 32);
    lrow = lrow * alpha + ps;

    {
      char* pbrow = (char*)&pbuf[wid][0][0] + c0 * 176;
#pragma unroll
      for (int f = 0; f < 4; ++f) {
        unsigned int u0 = cvtpk(sc[f][0], sc[f][1]);
        unsigned int u1 = cvtpk(sc[f][2], sc[f][3]);
        *(unsigned int*)(pbrow + (f * 16 + gi * 4) * 2)     = u0;
        *(unsigned int*)(pbrow + (f * 16 + gi * 4) * 2 + 4) = u1;
      }
    }
    asm volatile("s_waitcnt lgkmcnt(0)" ::: "memory");

    {
      const char* pb = (const char*)&pbuf[wid][0][0] + c0 * 176;
      const char* vcur = vbuf[tt & 1];
#pragma unroll
      for (int ks = 0; ks < 2; ++ks) {
        bf16x8 pa = *(const bf16x8*)(pb + ks * 64 + gi * 16);
#pragma unroll
        for (int df = 0; df < 4; ++df) {
          int rv = df * 16 + c0;
          int uL = ks * 4 + gi;
          bf16x8 vf = *(const bf16x8*)(vcur + rv * 128 + ((uL ^ (rv & 7)) * 16));
          o[df] = __builtin_amdgcn_mfma_f32_16x16x32_bf16(pa, vf, o[df], 0, 0, 0);
        }
      }
    }
  }

  unsigned short* po = pO + (size_t)pid * 4096;
#pragma unroll
  for (int i = 0; i < 4; ++i) {
    int r = wid * 16 + gi * 4 + i;
#pragma unroll
    for (int df = 0; df < 4; ++df)
      po[r * 64 + df * 16 + c0] = f2bf(o[df][i]);
  }
  if (lane < 16) {
    pm[pid * 64 + wid * 16 + c0] = mrow;
    pl[pid * 64 + wid * 16 + c0] = lrow;
  }
}

// ---------------- combine partials -> attn output [B*S, 1024] bf16 ----------
__global__ __launch_bounds__(256) void attn_combine(
    const unsigned short* __restrict__ pO,
    const float* __restrict__ pm,
    const float* __restrict__ pl,
    unsigned short* __restrict__ Out)
{
  int qt = blockIdx.x, bh = blockIdx.y;
  int t = threadIdx.x;
  int r = t >> 2, cseg = (t & 3) * 16;
  int pid0 = bh * 48 + qt;
  bool two = (qt >= 16);
  int pid1 = bh * 48 + 32 + qt - 16;

  float m0 = pm[pid0 * 64 + r];
  float l0 = pl[pid0 * 64 + r];
  float M = m0, w0 = 1.f, w1 = 0.f, l = l0;
  if (two) {
    float m1 = pm[pid1 * 64 + r];
    float l1 = pl[pid1 * 64 + r];
    M = fmaxf(m0, m1);
    w0 = exp2a(m0 - M);
    w1 = exp2a(m1 - M);
    l = w0 * l0 + w1 * l1;
  }
  float rl = 1.0f / l;

  const unsigned short* o0 = pO + (size_t)pid0 * 4096 + r * 64 + cseg;
  const unsigned short* o1 = pO + (size_t)pid1 * 4096 + r * 64 + cseg;
  int b = bh >> 4, h = bh & 15;
  size_t base = ((size_t)(b * S_LEN) + (qt * 64 + r)) * DM + h * DKH + cseg;

  bf16x8 a0 = *(const bf16x8*)o0;
  bf16x8 a1 = *(const bf16x8*)(o0 + 8);
  unsigned short res[16];
  if (two) {
    bf16x8 b0 = *(const bf16x8*)o1;
    bf16x8 b1 = *(const bf16x8*)(o1 + 8);
#pragma unroll
    for (int j = 0; j < 8; ++j) {
      res[j]     = f2bf((w0 * bf2f((unsigned short)a0[j]) + w1 * bf2f((unsigned short)b0[j])) * rl);
      res[j + 8] = f2bf((w0 * bf2f((unsigned short)a1[j]) + w1 * bf2f((unsigned short)b1[j])) * rl);
    }
  } else {
#pragma unroll
    for (int j = 0; j < 8; ++j) {
      res[j]     = f2bf(bf2f((unsigned short)a0[j]) * rl);
      res[j + 8] = f2bf(bf2f((unsigned short)a1[j]) * rl);
    }
  }
  *(u32x4*)(Out + base)     = *(u32x4*)res;
  *(u32x4*)(Out + base + 8) = *(u32x4*)(res + 8);
}

// ----------------------------------------------------------------------------
extern "C" void kernel_launch(void* const* d_in, const int* in_sizes, int n_in,
                              void* d_out, int out_size, void* d_ws, size_t ws_size,
                              hipStream_t stream) {
  const float* x       = (const float*)d_in[0];
  const float* w_atten = (const float*)d_in[1];
  const float* b_atten = (const float*)d_in[2];
  const float* w_proj  = (const float*)d_in[3];
  const float* b_proj  = (const float*)d_in[4];
  float* out = (float*)d_out;
  char* ws = (char*)d_ws;

  unsigned short* x_bf  = (unsigned short*)(ws);
  unsigned short* wa_bf = (unsigned short*)(ws + ((size_t)8  << 20));
  unsigned short* wp_bf = (unsigned short*)(ws + ((size_t)14 << 20));
  unsigned short* q_bf  = (unsigned short*)(ws + ((size_t)16 << 20));
  unsigned short* k_bf  = (unsigned short*)(ws + ((size_t)24 << 20));
  unsigned short* vt_bf = (unsigned short*)(ws + ((size_t)32 << 20));
  unsigned short* at_bf = (unsigned short*)(ws + ((size_t)40 << 20));
  // partial buffers overlay x_bf/wa_bf (dead after gemm0)
  unsigned short* pO = (unsigned short*)(ws);
  float* pm = (float*)(ws + 12582912);
  float* pl = (float*)(ws + 12976128);

  cvt_f32_to_bf16<<<2048, 256, 0, stream>>>(x, x_bf, 4194304);
  cvt_f32_to_bf16<<<1536, 256, 0, stream>>>(w_atten, wa_bf, 3145728);
  cvt_f32_to_bf16<<<512, 256, 0, stream>>>(w_proj, wp_bf, 1048576);

  gemm_x<0><<<dim3(24, 32), 256, 0, stream>>>(x_bf, wa_bf, b_atten, nullptr,
                                              q_bf, k_bf, vt_bf, 4096, 3072, 1024);
  attn_part<<<dim3(48, 32), 256, 0, stream>>>(q_bf, k_bf, vt_bf, pO, pm, pl);
  attn_combine<<<dim3(32, 32), 256, 0, stream>>>(pO, pm, pl, at_bf);
  gemm_x<1><<<dim3(8, 32), 256, 0, stream>>>(at_bf, wp_bf, b_proj, out,
                                             nullptr, nullptr, nullptr, 4096, 1024, 1024);
}

// Round 10
// 120.004 us; speedup vs baseline: 1.4090x; 1.0109x over previous
//
#include <hip/hip_runtime.h>
#include <hip/hip_bf16.h>

#define S_LEN 2048
#define NH 16
#define DKH 64
#define DM 1024
// 1/sqrt(64) * log2(e): folded into Q at the QKV-GEMM epilogue
#define QK_SCALE_L2E 0.1803368801111244f

typedef __attribute__((ext_vector_type(8))) short bf16x8;
typedef __attribute__((ext_vector_type(4))) float f32x4;
typedef __attribute__((ext_vector_type(4))) unsigned int u32x4;

__device__ __forceinline__ unsigned short f2bf(float f) {
  unsigned int x = __builtin_bit_cast(unsigned int, f);
  x += 0x7fffu + ((x >> 16) & 1u);   // RNE
  return (unsigned short)(x >> 16);
}
__device__ __forceinline__ float bf2f(unsigned short u) {
  unsigned int x = ((unsigned int)u) << 16;
  return __builtin_bit_cast(float, x);
}
__device__ __forceinline__ float exp2a(float x) {
  float r; asm("v_exp_f32 %0, %1" : "=v"(r) : "v"(x)); return r;
}
__device__ __forceinline__ unsigned int cvtpk(float a, float b) {
  unsigned int r; asm("v_cvt_pk_bf16_f32 %0, %1, %2" : "=v"(r) : "v"(a), "v"(b)); return r;
}

__device__ __forceinline__ void gload_lds16(const void* g, void* l) {
  __builtin_amdgcn_global_load_lds(
      (const __attribute__((address_space(1))) unsigned int*)g,
      (__attribute__((address_space(3))) unsigned int*)l, 16, 0, 0);
}

// ---------------- fp32 -> bf16 conversion (memory-bound pre-pass) -----------
__global__ void cvt_f32_to_bf16(const float* __restrict__ in,
                                unsigned short* __restrict__ out, int n) {
  int i = (blockIdx.x * blockDim.x + threadIdx.x) * 8;
  if (i >= n) return;
  float4 a = *(const float4*)(in + i);
  float4 b = *(const float4*)(in + i + 4);
  union { unsigned short us[8]; u32x4 v; } r;
  r.us[0] = f2bf(a.x); r.us[1] = f2bf(a.y); r.us[2] = f2bf(a.z); r.us[3] = f2bf(a.w);
  r.us[4] = f2bf(b.x); r.us[5] = f2bf(b.y); r.us[6] = f2bf(b.z); r.us[7] = f2bf(b.w);
  *(u32x4*)(out + i) = r.v;
}

// ==== 128x128 bf16 GEMM, BK=32, 3-slot LDS, depth-2 prefetch, XCD-chunked ===
// (unchanged from R9: 47us QKV, FETCH halved, conflicts 0)
template<int MODE>
__global__ __launch_bounds__(256, 3) void gemm_x(
    const unsigned short* __restrict__ A,   // [M,K] bf16 row-major
    const unsigned short* __restrict__ Bt,  // [N,K] bf16 row-major
    const float* __restrict__ bias,         // [N]
    float* __restrict__ Cf,                 // MODE 1
    unsigned short* __restrict__ qo,        // MODE 0
    unsigned short* __restrict__ ko,
    unsigned short* __restrict__ vto,
    int M, int N, int K)
{
  __shared__ __align__(16) char LA[3][8192];   // slot: 128 rows x 32 bf16
  __shared__ __align__(16) char LB[3][8192];   // 2 rows packed per 128B line
  int t = threadIdx.x;
  int lane = t & 63, wid = t >> 6;
  int wr = wid >> 1, wc = wid & 1;

  int bid = blockIdx.x + gridDim.x * blockIdx.y;
  int xcd = bid & 7, local = bid >> 3;
  int bx, by;
  if (MODE == 0) {
    int xm = xcd >> 1, xn = xcd & 1;        // 4 x 2 XCD layout
    by = xm * 8 + (local & 7);              // local in [0,96)
    bx = xn * 12 + (local >> 3);
  } else {
    by = xcd * 4 + (local >> 3);            // local in [0,32)
    bx = local & 7;
  }
  int m0 = by << 7, n0 = bx << 7;
  int gi = lane >> 4, c0 = lane & 15;
  int rs = t >> 3, uP = t & 7;               // rs in [0,32)

  f32x4 acc[4][4];
#pragma unroll
  for (int i = 0; i < 4; ++i)
#pragma unroll
    for (int j = 0; j < 4; ++j) acc[i][j] = (f32x4){0.f, 0.f, 0.f, 0.f};

  // staging (rule 21): LDS line p, slot s holds row 2p+(u>>2), chunk u&3,
  // u = s^(p&7).
  int u = uP ^ (rs & 7);
  int srow = 2 * rs + (u >> 2);
  int scol = (u & 3) * 8;
  const unsigned short* ap0 = A  + (size_t)(m0 + srow) * K + scol;
  const unsigned short* ap1 = ap0 + (size_t)64 * K;
  const unsigned short* bp0 = Bt + (size_t)(n0 + srow) * K + scol;
  const unsigned short* bp1 = bp0 + (size_t)64 * K;
  int la0 = rs * 128 + uP * 16, la1 = la0 + 4096;

#define STG(s)                                                     \
  do {                                                             \
    gload_lds16(ap0, LA[s] + la0); gload_lds16(ap1, LA[s] + la1);  \
    gload_lds16(bp0, LB[s] + la0); gload_lds16(bp1, LB[s] + la1);  \
    ap0 += 32; ap1 += 32; bp0 += 32; bp1 += 32;                    \
  } while (0)

  const int NT = K >> 5;                     // 32 tiles at K=1024
  STG(0); STG(1);                            // depth-2 prologue (8 loads)

  int cs = 0, ss = 2;
  for (int kt = 0; kt < NT; ++kt) {
    if (kt < NT - 1) asm volatile("s_waitcnt vmcnt(4)" ::: "memory");
    else             asm volatile("s_waitcnt vmcnt(0)" ::: "memory");
    __builtin_amdgcn_s_barrier();

    const char* cA = LA[cs];
    const char* cB = LB[cs];
    bf16x8 af[4], bfr[4];
#pragma unroll
    for (int m = 0; m < 4; ++m) {
      int ra = wr * 64 + m * 16 + c0;
      int p = ra >> 1;
      af[m] = *(const bf16x8*)(cA + p * 128 + ((((ra & 1) * 4 + gi) ^ (p & 7)) * 16));
    }
#pragma unroll
    for (int n = 0; n < 4; ++n) {
      int rb = wc * 64 + n * 16 + c0;
      int p = rb >> 1;
      bfr[n] = *(const bf16x8*)(cB + p * 128 + ((((rb & 1) * 4 + gi) ^ (p & 7)) * 16));
    }
    if (kt < NT - 2) STG(ss);                // keep 2 tiles in flight

    __builtin_amdgcn_s_setprio(1);
#pragma unroll
    for (int m = 0; m < 4; ++m)
#pragma unroll
      for (int n = 0; n < 4; ++n)
        acc[m][n] = __builtin_amdgcn_mfma_f32_16x16x32_bf16(af[m], bfr[n], acc[m][n], 0, 0, 0);
    __builtin_amdgcn_s_setprio(0);

    cs = (cs == 2) ? 0 : cs + 1;
    ss = (ss == 2) ? 0 : ss + 1;
  }
#undef STG

#pragma unroll
  for (int i = 0; i < 4; ++i) {
#pragma unroll
    for (int j = 0; j < 4; ++j) {
#pragma unroll
      for (int rI = 0; rI < 4; ++rI) {
        int m = m0 + wr * 64 + i * 16 + gi * 4 + rI;
        int n = n0 + wc * 64 + j * 16 + c0;
        float v = acc[i][j][rI] + bias[n];
        if (MODE == 1) {
          Cf[(size_t)m * N + n] = v;
        } else {
          int b = m >> 11, s = m & 2047;
          int which = n >> 10, w2 = n & 1023;
          int h = w2 >> 6, dk = w2 & 63;
          size_t hoff = (size_t)(b * NH + h);
          if (which == 0) {
            qo[(hoff * S_LEN + s) * DKH + dk] = f2bf(v * QK_SCALE_L2E);
          } else if (which == 1) {
            ko[(hoff * S_LEN + s) * DKH + dk] = f2bf(v);
          } else {
            vto[(hoff * DKH + dk) * S_LEN + s] = f2bf(v);  // V transposed
          }
        }
      }
    }
  }
}

// ==== 128x64 bf16 GEMM for proj: 512 blocks -> 2 blocks/CU TLP ==============
// Same BK=32 / 3-slot / depth-2 / packed-XOR structure as gemm_x; B tile is
// 64x32 (one staging round). Grid (16,32); each XCD owns 4 m-rows x 16 n-cols
// (A 1MB + B 2MB = 3MB, L2-resident). 36KB LDS -> 4 blocks/CU capacity.
__global__ __launch_bounds__(256, 4) void gemm_h(
    const unsigned short* __restrict__ A,   // [M,K] bf16 row-major
    const unsigned short* __restrict__ Bt,  // [N,K] bf16 row-major
    const float* __restrict__ bias,         // [N]
    float* __restrict__ Cf,                 // [M,N] fp32 out
    int M, int N, int K)
{
  __shared__ __align__(16) char LA[3][8192];   // 128 rows x 32 bf16
  __shared__ __align__(16) char LB[3][4096];   // 64 rows x 32 bf16
  int t = threadIdx.x;
  int lane = t & 63, wid = t >> 6;
  int wr = wid >> 1, wc = wid & 1;

  // XCD chunk: grid (16,32) -> 512 blocks; xcd owns by in [4*xcd,4*xcd+4)
  int bid = blockIdx.x + gridDim.x * blockIdx.y;
  int xcd = bid & 7, local = bid >> 3;      // local in [0,64)
  int by = xcd * 4 + (local >> 4);
  int bx = local & 15;
  int m0 = by << 7, n0 = bx << 6;
  int gi = lane >> 4, c0 = lane & 15;
  int rs = t >> 3, uP = t & 7;               // rs in [0,32)

  f32x4 acc[4][2];
#pragma unroll
  for (int i = 0; i < 4; ++i)
#pragma unroll
    for (int j = 0; j < 2; ++j) acc[i][j] = (f32x4){0.f, 0.f, 0.f, 0.f};

  int u = uP ^ (rs & 7);
  int srow = 2 * rs + (u >> 2);
  int scol = (u & 3) * 8;
  const unsigned short* ap0 = A  + (size_t)(m0 + srow) * K + scol;
  const unsigned short* ap1 = ap0 + (size_t)64 * K;
  const unsigned short* bp0 = Bt + (size_t)(n0 + srow) * K + scol;
  int la0 = rs * 128 + uP * 16, la1 = la0 + 4096;

#define STGH(s)                                                    \
  do {                                                             \
    gload_lds16(ap0, LA[s] + la0); gload_lds16(ap1, LA[s] + la1);  \
    gload_lds16(bp0, LB[s] + la0);                                 \
    ap0 += 32; ap1 += 32; bp0 += 32;                               \
  } while (0)

  const int NT = K >> 5;
  STGH(0); STGH(1);                          // depth-2 prologue (6 loads)

  int cs = 0, ss = 2;
  for (int kt = 0; kt < NT; ++kt) {
    if (kt < NT - 1) asm volatile("s_waitcnt vmcnt(3)" ::: "memory");
    else             asm volatile("s_waitcnt vmcnt(0)" ::: "memory");
    __builtin_amdgcn_s_barrier();

    const char* cA = LA[cs];
    const char* cB = LB[cs];
    bf16x8 af[4], bfr[2];
#pragma unroll
    for (int m = 0; m < 4; ++m) {
      int ra = wr * 64 + m * 16 + c0;
      int p = ra >> 1;
      af[m] = *(const bf16x8*)(cA + p * 128 + ((((ra & 1) * 4 + gi) ^ (p & 7)) * 16));
    }
#pragma unroll
    for (int n = 0; n < 2; ++n) {
      int rb = wc * 32 + n * 16 + c0;
      int p = rb >> 1;
      bfr[n] = *(const bf16x8*)(cB + p * 128 + ((((rb & 1) * 4 + gi) ^ (p & 7)) * 16));
    }
    if (kt < NT - 2) STGH(ss);

    __builtin_amdgcn_s_setprio(1);
#pragma unroll
    for (int m = 0; m < 4; ++m)
#pragma unroll
      for (int n = 0; n < 2; ++n)
        acc[m][n] = __builtin_amdgcn_mfma_f32_16x16x32_bf16(af[m], bfr[n], acc[m][n], 0, 0, 0);
    __builtin_amdgcn_s_setprio(0);

    cs = (cs == 2) ? 0 : cs + 1;
    ss = (ss == 2) ? 0 : ss + 1;
  }
#undef STGH

  float bias_v[2];
#pragma unroll
  for (int n = 0; n < 2; ++n) bias_v[n] = bias[n0 + wc * 32 + n * 16 + c0];

#pragma unroll
  for (int i = 0; i < 4; ++i) {
#pragma unroll
    for (int j = 0; j < 2; ++j) {
#pragma unroll
      for (int rI = 0; rI < 4; ++rI) {
        int m = m0 + wr * 64 + i * 16 + gi * 4 + rI;
        int n = n0 + wc * 32 + j * 16 + c0;
        Cf[(size_t)m * N + n] = acc[i][j][rI] + bias_v[j];
      }
    }
  }
}

// ---------------- split-KV flash attention work table (LPT order) -----------
struct WorkItem { unsigned char qt, t0, nt; };
__device__ __constant__ WorkItem g_items[48] = {
  {15,0,16},
  {16,0,16},{17,0,16},{18,0,16},{19,0,16},{20,0,16},{21,0,16},{22,0,16},{23,0,16},
  {24,0,16},{25,0,16},{26,0,16},{27,0,16},{28,0,16},{29,0,16},{30,0,16},{31,0,16},
  {31,16,16},
  {14,0,15},{30,16,15},
  {13,0,14},{29,16,14},
  {12,0,13},{28,16,13},
  {11,0,12},{27,16,12},
  {10,0,11},{26,16,11},
  { 9,0,10},{25,16,10},
  { 8,0, 9},{24,16, 9},
  { 7,0, 8},{23,16, 8},
  { 6,0, 7},{22,16, 7},
  { 5,0, 6},{21,16, 6},
  { 4,0, 5},{20,16, 5},
  { 3,0, 4},{19,16, 4},
  { 2,0, 3},{18,16, 3},
  { 1,0, 2},{17,16, 2},
  { 0,0, 1},{16,16, 1},
};

// ---------------- flash attention (partial), swapped-QK^T in-reg softmax ----
__global__ __launch_bounds__(256) void attn_part(
    const unsigned short* __restrict__ Q,   // [BH, S, 64] bf16, pre-scaled
    const unsigned short* __restrict__ Kb,  // [BH, S, 64] bf16
    const unsigned short* __restrict__ Vt,  // [BH, 64, S] bf16
    unsigned short* __restrict__ pO,        // [1536][64][64] bf16
    float* __restrict__ pm,                 // [1536][64]
    float* __restrict__ pl)                 // [1536][64]
{
  __shared__ __align__(16) char kbuf[64 * 128];
  __shared__ __align__(16) char vbuf[2][64 * 128];
  __shared__ __align__(16) unsigned short pbuf[4][16][88];  // 176B rows
  int t = threadIdx.x;
  int lane = t & 63, wid = t >> 6;
  int gi = lane >> 4, c0 = lane & 15;
  int bid = blockIdx.x + 48 * blockIdx.y;
  int xcd = bid & 7, local = bid >> 3;      // local in [0,192)
  int item = local >> 2;
  int bh = xcd * 4 + (local & 3);
  WorkItem wi = g_items[item];
  int qt = wi.qt, tile0 = wi.t0, nt = wi.nt;
  int pid = bh * 48 + (tile0 ? (32 + qt - 16) : qt);
  int q0 = qt << 6;
  const unsigned short* Qh = Q  + (size_t)bh * S_LEN * DKH;
  const unsigned short* Kh = Kb + (size_t)bh * S_LEN * DKH;
  const unsigned short* Vh = Vt + (size_t)bh * DKH * S_LEN;

  bf16x8 qf[2];
  {
    int qrow = q0 + wid * 16 + c0;
#pragma unroll
    for (int ks = 0; ks < 2; ++ks)
      qf[ks] = *(const bf16x8*)(Qh + (size_t)qrow * DKH + ks * 32 + gi * 8);
  }

  float mrow = -1e30f, lrow = 0.f;
  f32x4 o[4];
#pragma unroll
  for (int i = 0; i < 4; ++i) o[i] = (f32x4){0, 0, 0, 0};

  int rs = t >> 3, uP = t & 7;
  int q_abs = q0 + wid * 16 + c0;

  int c8 = uP ^ (rs & 7);
  const unsigned short* kp0 = Kh + ((size_t)(tile0 * 64 + rs) * DKH) + c8 * 8;
  const unsigned short* kp1 = kp0 + 32 * DKH;
  const unsigned short* vp0 = Vh + (size_t)rs * S_LEN + tile0 * 64 + c8 * 8;
  const unsigned short* vp1 = vp0 + (size_t)32 * S_LEN;
  char* klds0 = kbuf + rs * 128 + uP * 16;
  char* klds1 = klds0 + 32 * 128;
  int vlds_off0 = rs * 128 + uP * 16;

  gload_lds16(kp0, klds0);
  gload_lds16(kp1, klds1);
  gload_lds16(vp0, vbuf[0] + vlds_off0);
  gload_lds16(vp1, vbuf[0] + vlds_off0 + 32 * 128);
  kp0 += 64 * DKH; kp1 += 64 * DKH; vp0 += 64; vp1 += 64;

  for (int tt = 0; tt < nt; ++tt) {
    int tile = tile0 + tt;
    int kv0 = tile << 6;
    __syncthreads();   // staged K(t), V(t) landed

    // S^T = K * Q^T: sc[f][i] = S[q=c0][kv = kv0 + f*16 + gi*4 + i]
    f32x4 sc[4];
#pragma unroll
    for (int f = 0; f < 4; ++f) {
      f32x4 s = (f32x4){0, 0, 0, 0};
#pragma unroll
      for (int ks = 0; ks < 2; ++ks) {
        int rb = f * 16 + c0;
        int uL = ks * 4 + gi;
        bf16x8 kf = *(const bf16x8*)(kbuf + rb * 128 + ((uL ^ (rb & 7)) * 16));
        s = __builtin_amdgcn_mfma_f32_16x16x32_bf16(kf, qf[ks], s, 0, 0, 0);
      }
      sc[f] = s;
    }
    __syncthreads();   // all waves done reading kbuf

    if (tt + 1 < nt) {
      char* vb = vbuf[(tt + 1) & 1];
      gload_lds16(kp0, klds0);
      gload_lds16(kp1, klds1);
      gload_lds16(vp0, vb + vlds_off0);
      gload_lds16(vp1, vb + vlds_off0 + 32 * 128);
      kp0 += 64 * DKH; kp1 += 64 * DKH; vp0 += 64; vp1 += 64;
    }

    if (tile == qt) {
      int kvb = kv0 + gi * 4;
#pragma unroll
      for (int f = 0; f < 4; ++f)
#pragma unroll
        for (int i = 0; i < 4; ++i)
          if (kvb + f * 16 + i > q_abs) sc[f][i] = -1e30f;
    }

    float m01 = fmaxf(fmaxf(sc[0][0], sc[0][1]), fmaxf(sc[0][2], sc[0][3]));
    float m23 = fmaxf(fmaxf(sc[1][0], sc[1][1]), fmaxf(sc[1][2], sc[1][3]));
    float m45 = fmaxf(fmaxf(sc[2][0], sc[2][1]), fmaxf(sc[2][2], sc[2][3]));
    float m67 = fmaxf(fmaxf(sc[3][0], sc[3][1]), fmaxf(sc[3][2], sc[3][3]));
    float tmax = fmaxf(fmaxf(m01, m23), fmaxf(m45, m67));
    tmax = fmaxf(tmax, __shfl_xor(tmax, 16));
    tmax = fmaxf(tmax, __shfl_xor(tmax, 32));

    float alpha = 1.f;
    if (__any(tmax > mrow)) {
      float mnew = fmaxf(mrow, tmax);
      alpha = exp2a(mrow - mnew);
      mrow = mnew;
      float af0 = __shfl(alpha, gi * 4 + 0);
      float af1 = __shfl(alpha, gi * 4 + 1);
      float af2 = __shfl(alpha, gi * 4 + 2);
      float af3 = __shfl(alpha, gi * 4 + 3);
#pragma unroll
      for (int df = 0; df < 4; ++df) {
        o[df][0] *= af0; o[df][1] *= af1; o[df][2] *= af2; o[df][3] *= af3;
      }
    }

    float ps0 = 0, ps1 = 0, ps2 = 0, ps3 = 0;
#pragma unroll
    for (int f = 0; f < 4; ++f) {
      float p0 = exp2a(sc[f][0] - mrow);
      float p1 = exp2a(sc[f][1] - mrow);
      float p2 = exp2a(sc[f][2] - mrow);
      float p3 = exp2a(sc[f][3] - mrow);
      sc[f][0] = p0; sc[f][1] = p1; sc[f][2] = p2; sc[f][3] = p3;
      ps0 += p0; ps1 += p1; ps2 += p2; ps3 += p3;
    }
    float ps = (ps0 + ps1) + (ps2 + ps3);
    ps += __shfl_xor(ps, 16);
    ps += __shfl_xor(ps, 32);
    lrow = lrow * alpha + ps;

    {
      char* pbrow = (char*)&pbuf[wid][0][0] + c0 * 176;
#pragma unroll
      for (int f = 0; f < 4; ++f) {
        unsigned int u0 = cvtpk(sc[f][0], sc[f][1]);
        unsigned int u1 = cvtpk(sc[f][2], sc[f][3]);
        *(unsigned int*)(pbrow + (f * 16 + gi * 4) * 2)     = u0;
        *(unsigned int*)(pbrow + (f * 16 + gi * 4) * 2 + 4) = u1;
      }
    }
    asm volatile("s_waitcnt lgkmcnt(0)" ::: "memory");

    {
      const char* pb = (const char*)&pbuf[wid][0][0] + c0 * 176;
      const char* vcur = vbuf[tt & 1];
#pragma unroll
      for (int ks = 0; ks < 2; ++ks) {
        bf16x8 pa = *(const bf16x8*)(pb + ks * 64 + gi * 16);
#pragma unroll
        for (int df = 0; df < 4; ++df) {
          int rv = df * 16 + c0;
          int uL = ks * 4 + gi;
          bf16x8 vf = *(const bf16x8*)(vcur + rv * 128 + ((uL ^ (rv & 7)) * 16));
          o[df] = __builtin_amdgcn_mfma_f32_16x16x32_bf16(pa, vf, o[df], 0, 0, 0);
        }
      }
    }
  }

  unsigned short* po = pO + (size_t)pid * 4096;
#pragma unroll
  for (int i = 0; i < 4; ++i) {
    int r = wid * 16 + gi * 4 + i;
#pragma unroll
    for (int df = 0; df < 4; ++df)
      po[r * 64 + df * 16 + c0] = f2bf(o[df][i]);
  }
  if (lane < 16) {
    pm[pid * 64 + wid * 16 + c0] = mrow;
    pl[pid * 64 + wid * 16 + c0] = lrow;
  }
}

// ---------------- combine partials -> attn output [B*S, 1024] bf16 ----------
__global__ __launch_bounds__(256) void attn_combine(
    const unsigned short* __restrict__ pO,
    const float* __restrict__ pm,
    const float* __restrict__ pl,
    unsigned short* __restrict__ Out)
{
  int qt = blockIdx.x, bh = blockIdx.y;
  int t = threadIdx.x;
  int r = t >> 2, cseg = (t & 3) * 16;
  int pid0 = bh * 48 + qt;
  bool two = (qt >= 16);
  int pid1 = bh * 48 + 32 + qt - 16;

  float m0 = pm[pid0 * 64 + r];
  float l0 = pl[pid0 * 64 + r];
  float M = m0, w0 = 1.f, w1 = 0.f, l = l0;
  if (two) {
    float m1 = pm[pid1 * 64 + r];
    float l1 = pl[pid1 * 64 + r];
    M = fmaxf(m0, m1);
    w0 = exp2a(m0 - M);
    w1 = exp2a(m1 - M);
    l = w0 * l0 + w1 * l1;
  }
  float rl = 1.0f / l;

  const unsigned short* o0 = pO + (size_t)pid0 * 4096 + r * 64 + cseg;
  const unsigned short* o1 = pO + (size_t)pid1 * 4096 + r * 64 + cseg;
  int b = bh >> 4, h = bh & 15;
  size_t base = ((size_t)(b * S_LEN) + (qt * 64 + r)) * DM + h * DKH + cseg;

  bf16x8 a0 = *(const bf16x8*)o0;
  bf16x8 a1 = *(const bf16x8*)(o0 + 8);
  unsigned short res[16];
  if (two) {
    bf16x8 b0 = *(const bf16x8*)o1;
    bf16x8 b1 = *(const bf16x8*)(o1 + 8);
#pragma unroll
    for (int j = 0; j < 8; ++j) {
      res[j]     = f2bf((w0 * bf2f((unsigned short)a0[j]) + w1 * bf2f((unsigned short)b0[j])) * rl);
      res[j + 8] = f2bf((w0 * bf2f((unsigned short)a1[j]) + w1 * bf2f((unsigned short)b1[j])) * rl);
    }
  } else {
#pragma unroll
    for (int j = 0; j < 8; ++j) {
      res[j]     = f2bf(bf2f((unsigned short)a0[j]) * rl);
      res[j + 8] = f2bf(bf2f((unsigned short)a1[j]) * rl);
    }
  }
  *(u32x4*)(Out + base)     = *(u32x4*)res;
  *(u32x4*)(Out + base + 8) = *(u32x4*)(res + 8);
}

// ----------------------------------------------------------------------------
extern "C" void kernel_launch(void* const* d_in, const int* in_sizes, int n_in,
                              void* d_out, int out_size, void* d_ws, size_t ws_size,
                              hipStream_t stream) {
  const float* x       = (const float*)d_in[0];
  const float* w_atten = (const float*)d_in[1];
  const float* b_atten = (const float*)d_in[2];
  const float* w_proj  = (const float*)d_in[3];
  const float* b_proj  = (const float*)d_in[4];
  float* out = (float*)d_out;
  char* ws = (char*)d_ws;

  unsigned short* x_bf  = (unsigned short*)(ws);
  unsigned short* wa_bf = (unsigned short*)(ws + ((size_t)8  << 20));
  unsigned short* wp_bf = (unsigned short*)(ws + ((size_t)14 << 20));
  unsigned short* q_bf  = (unsigned short*)(ws + ((size_t)16 << 20));
  unsigned short* k_bf  = (unsigned short*)(ws + ((size_t)24 << 20));
  unsigned short* vt_bf = (unsigned short*)(ws + ((size_t)32 << 20));
  unsigned short* at_bf = (unsigned short*)(ws + ((size_t)40 << 20));
  // partial buffers overlay x_bf/wa_bf (dead after gemm0)
  unsigned short* pO = (unsigned short*)(ws);
  float* pm = (float*)(ws + 12582912);
  float* pl = (float*)(ws + 12976128);

  cvt_f32_to_bf16<<<2048, 256, 0, stream>>>(x, x_bf, 4194304);
  cvt_f32_to_bf16<<<1536, 256, 0, stream>>>(w_atten, wa_bf, 3145728);
  cvt_f32_to_bf16<<<512, 256, 0, stream>>>(w_proj, wp_bf, 1048576);

  gemm_x<0><<<dim3(24, 32), 256, 0, stream>>>(x_bf, wa_bf, b_atten, nullptr,
                                              q_bf, k_bf, vt_bf, 4096, 3072, 1024);
  attn_part<<<dim3(48, 32), 256, 0, stream>>>(q_bf, k_bf, vt_bf, pO, pm, pl);
  attn_combine<<<dim3(32, 32), 256, 0, stream>>>(pO, pm, pl, at_bf);
  gemm_h<<<dim3(16, 32), 256, 0, stream>>>(at_bf, wp_bf, b_proj, out,
                                           4096, 1024, 1024);
}